// Round 11
// baseline (563.357 us; speedup 1.0000x reference)
//
#include <hip/hip_runtime.h>
#include <hip/hip_bf16.h>

// ---------- bf16 helpers (raw ushort storage) ----------
__device__ __forceinline__ float b2f(unsigned short u) {
    union { float f; unsigned int i; } v; v.i = ((unsigned int)u) << 16; return v.f;
}
__device__ __forceinline__ unsigned short f2b(float f) {
    union { float f; unsigned int i; } v; v.f = f;
    unsigned int i = v.i;
    return (unsigned short)((i + 0x7FFFu + ((i >> 16) & 1u)) >> 16);   // RNE
}

typedef __bf16 bf16x8 __attribute__((ext_vector_type(8)));
typedef float  f32x4  __attribute__((ext_vector_type(4)));

// 256-col LDS tile: row stride 256, XOR-16B swizzle
__device__ __forceinline__ int idx256(int r, int c) {
    return r * 256 + (((c >> 3) ^ (r & 31)) << 3) + (c & 7);
}
// 128-col LDS tile
__device__ __forceinline__ int idx128(int r, int c) {
    return r * 128 + ((((c >> 3) ^ r) & 15) << 3) + (c & 7);
}

// ---------- prep: xb[M][128] = bf16([x | t]); out[t_pred] = 0; count = 0 -----
__global__ __launch_bounds__(256) void prep_xb_kernel(
    const float* __restrict__ x, const float* __restrict__ t,
    unsigned short* __restrict__ xb, float* __restrict__ out,
    int* __restrict__ count, int M)
{
    int idx = blockIdx.x * 256 + threadIdx.x;          // over M*128
    if (idx < M * 128) {
        int i = idx >> 7, j = idx & 127;
        xb[idx] = f2b((j < 127) ? x[(size_t)i * 127 + j] : t[i]);
    }
    if (idx < M) { out[idx] = 0.0f; count[idx] = 0; }
}

// ---------- fallback prep: agg = 0; out[t_pred] = 0 ----------
__global__ __launch_bounds__(256) void prep_kernel(unsigned short* __restrict__ agg,
                                                   float* __restrict__ out, int M)
{
    int idx = blockIdx.x * 256 + threadIdx.x;
    if (idx < M * 128) agg[idx] = 0;
    if (idx < M) out[idx] = 0.0f;
}

// ---------- fallback scatter: bf16 packed global atomics ----------
__global__ __launch_bounds__(256) void scatter_kernel(
    const int* __restrict__ ei, const float* __restrict__ x,
    const float* __restrict__ t, unsigned short* __restrict__ agg, int E, int M)
{
    int e = blockIdx.x * 8 + (threadIdx.x >> 5);
    if (e >= E) return;
    int lane = threadIdx.x & 31;
    int s = ei[e];
    int d = ei[E + e];
    if ((unsigned)s >= (unsigned)M || (unsigned)d >= (unsigned)M) return;
    int f0 = lane * 4;
    const float* xr = x + (size_t)s * 127;
    float v0 = xr[f0];
    float v1 = xr[f0 + 1];
    float v2 = xr[f0 + 2];
    float v3 = (f0 + 3 < 127) ? xr[f0 + 3] : t[s];
    __hip_bfloat162* dp = (__hip_bfloat162*)(agg + (size_t)d * 128 + f0);
    __hip_bfloat162 a; a.x = __float2bfloat16(v0); a.y = __float2bfloat16(v1);
    __hip_bfloat162 b; b.x = __float2bfloat16(v2); b.y = __float2bfloat16(v3);
    unsafeAtomicAdd(dp,     a);
    unsafeAtomicAdd(dp + 1, b);
}

// ---------- S1: per-node in-degree histogram ----------
__global__ __launch_bounds__(256) void hist_node_kernel(
    const int* __restrict__ ei, int* __restrict__ count, int E, int M)
{
    int e = blockIdx.x * 256 + threadIdx.x;
    if (e >= E) return;
    int s = ei[e];
    int d = ei[E + e];
    if ((unsigned)s < (unsigned)M && (unsigned)d < (unsigned)M)
        atomicAdd(&count[d], 1);
}

// ---------- S2: exclusive scan over M node counts (1 block, 1024 thr) --------
__global__ __launch_bounds__(1024) void scan_node_kernel(
    const int* __restrict__ count, int* __restrict__ start,
    int* __restrict__ cursor, int M)
{
    __shared__ int tsum[1024];
    int tid = threadIdx.x;
    int chunk = (M + 1023) >> 10;
    int lo = tid * chunk;
    int hi = lo + chunk; if (hi > M) hi = M;
    int s = 0;
    for (int i = lo; i < hi; ++i) s += count[i];
    tsum[tid] = s;
    __syncthreads();
    for (int off = 1; off < 1024; off <<= 1) {
        int a = (tid >= off) ? tsum[tid - off] : 0;
        __syncthreads();
        tsum[tid] += a;
        __syncthreads();
    }
    int run = tsum[tid] - s;
    for (int i = lo; i < hi; ++i) {
        start[i] = run;
        cursor[i] = run;
        run += count[i];
    }
    if (tid == 1023) start[M] = run;
}

// ---------- S3: reorder srcs into dst-sorted CSR order ----------
__global__ __launch_bounds__(256) void reorder_csr_kernel(
    const int* __restrict__ ei, int* __restrict__ cursor,
    int* __restrict__ sorted, int E, int M)
{
    int e = blockIdx.x * 256 + threadIdx.x;
    if (e >= E) return;
    int s = ei[e];
    int d = ei[E + e];
    if ((unsigned)s < (unsigned)M && (unsigned)d < (unsigned)M) {
        int slot = atomicAdd(&cursor[d], 1);
        sorted[slot] = s;
    }
}

// ---------- pack fp32 weight B[K x 256] -> hi/lo bf16 planes, MFMA B order ----
__global__ __launch_bounds__(256) void pack_kernel(
    const float* __restrict__ B, unsigned short* __restrict__ Bhi,
    unsigned short* __restrict__ Blo, int K)
{
    int idx = blockIdx.x * 256 + threadIdx.x;
    if (idx >= K * 256) return;
    int j    = idx & 7;
    int lane = (idx >> 3) & 63;
    int nt   = (idx >> 9) & 15;
    int kt   = idx >> 13;
    int k = kt * 32 + ((lane >> 4) * 8) + j;
    int n = nt * 16 + (lane & 15);
    float w = B[k * 256 + n];
    unsigned short hi = f2b(w);
    Bhi[idx] = hi;
    Blo[idx] = f2b(w - b2f(hi));
}

// ---------- mega: fused CSR gather + 4 GEMMs + final dot -------------------
// FUSED: prologue gathers in-edge sums (CSR) + self row straight into LDS U.
// No agg buffer, no separate gather kernel. One 32 KB in-place LDS buffer.
// __launch_bounds__(256,3): cap VGPR ~170 (R10 measured 172 -> 2 waves/SIMD;
// a 4-reg shave buys 3 waves/SIMD). R9 showed aggressive caps (64) spill
// catastrophically; this is a minimal shave. Tripwire: WRITE_SIZE >> 0.2 MB.
template<bool FUSED>
__global__ __launch_bounds__(256, 3) void mega_kernel(
    const float* __restrict__ x, const float* __restrict__ t,
    const unsigned short* __restrict__ xb,
    const unsigned short* __restrict__ aggbf,     // tier-C only
    const int* __restrict__ start, const int* __restrict__ sorted,
    const unsigned short* __restrict__ W1h, const unsigned short* __restrict__ W1l,
    const float* __restrict__ b1,
    const unsigned short* __restrict__ W2h, const unsigned short* __restrict__ W2l,
    const float* __restrict__ b2,
    const unsigned short* __restrict__ P1h, const unsigned short* __restrict__ P1l,
    const float* __restrict__ pb1,
    const unsigned short* __restrict__ P2h, const unsigned short* __restrict__ P2l,
    const float* __restrict__ pb2,
    const float* __restrict__ P3, const float* __restrict__ pb3,
    float* __restrict__ out, int M)
{
    __shared__ unsigned short U[64 * 256];   // 32 KB: h_in -> h1 -> h -> p1
    __shared__ float red[256];               // 1 KB

    const int wave = threadIdx.x >> 6;
    const int lane = threadIdx.x & 63;
    const int lr   = lane & 15;
    const int quad = lane >> 4;
    const int lk   = quad * 8;
    const int rbase = quad * 4;
    const int row0 = blockIdx.x * 64;
    const int ntg0 = wave * 4;

    // ---- prologue: U := bf16(h_in) ----
    if (FUSED) {
        // half-wave per node: self row + CSR in-edge sum, 4-edge unrolled
        int hw = threadIdx.x >> 5;           // 0..7
        int ln = threadIdx.x & 31;
        for (int rr = hw; rr < 64; rr += 8) {
            int node = row0 + rr; if (node >= M) node = M - 1;
            int s0 = start[node], s1 = start[node + 1];
            uint2 sf = *(const uint2*)(xb + (size_t)node * 128 + ln * 4);
            float a0 = b2f((unsigned short)(sf.x & 0xffff));
            float a1 = b2f((unsigned short)(sf.x >> 16));
            float a2 = b2f((unsigned short)(sf.y & 0xffff));
            float a3 = b2f((unsigned short)(sf.y >> 16));
            for (int i = s0; i < s1; i += 4) {
                int last = s1 - 1;
                int i1 = i + 1 < s1 ? i + 1 : last;
                int i2 = i + 2 < s1 ? i + 2 : last;
                int i3 = i + 3 < s1 ? i + 3 : last;
                int src0 = sorted[i],  src1 = sorted[i1];
                int src2 = sorted[i2], src3 = sorted[i3];
                uint2 r0 = *(const uint2*)(xb + (size_t)src0 * 128 + ln * 4);
                uint2 r1 = *(const uint2*)(xb + (size_t)src1 * 128 + ln * 4);
                uint2 r2 = *(const uint2*)(xb + (size_t)src2 * 128 + ln * 4);
                uint2 r3 = *(const uint2*)(xb + (size_t)src3 * 128 + ln * 4);
                a0 += b2f((unsigned short)(r0.x & 0xffff));
                a1 += b2f((unsigned short)(r0.x >> 16));
                a2 += b2f((unsigned short)(r0.y & 0xffff));
                a3 += b2f((unsigned short)(r0.y >> 16));
                if (i + 1 < s1) {
                    a0 += b2f((unsigned short)(r1.x & 0xffff));
                    a1 += b2f((unsigned short)(r1.x >> 16));
                    a2 += b2f((unsigned short)(r1.y & 0xffff));
                    a3 += b2f((unsigned short)(r1.y >> 16));
                }
                if (i + 2 < s1) {
                    a0 += b2f((unsigned short)(r2.x & 0xffff));
                    a1 += b2f((unsigned short)(r2.x >> 16));
                    a2 += b2f((unsigned short)(r2.y & 0xffff));
                    a3 += b2f((unsigned short)(r2.y >> 16));
                }
                if (i + 3 < s1) {
                    a0 += b2f((unsigned short)(r3.x & 0xffff));
                    a1 += b2f((unsigned short)(r3.x >> 16));
                    a2 += b2f((unsigned short)(r3.y & 0xffff));
                    a3 += b2f((unsigned short)(r3.y >> 16));
                }
            }
            uint2 w;
            w.x = (unsigned)f2b(a0) | ((unsigned)f2b(a1) << 16);
            w.y = (unsigned)f2b(a2) | ((unsigned)f2b(a3) << 16);
            *(uint2*)&U[idx128(rr, ln * 4)] = w;   // 8B-aligned (offset mult of 8)
        }
    } else {
        // tier C: h_in = xb-less raw gather + bf16 agg
        int r = threadIdx.x >> 2;
        int q = threadIdx.x & 3;
        int gr = row0 + r; if (gr >= M) gr = M - 1;
        #pragma unroll
        for (int c8 = 0; c8 < 4; ++c8) {
            int c0 = q * 32 + c8 * 8;
            const unsigned short* ar = aggbf + (size_t)gr * 128 + c0;
            uint4 u = *(const uint4*)ar;
            float av[8];
            av[0]=b2f((unsigned short)(u.x&0xffff)); av[1]=b2f((unsigned short)(u.x>>16));
            av[2]=b2f((unsigned short)(u.y&0xffff)); av[3]=b2f((unsigned short)(u.y>>16));
            av[4]=b2f((unsigned short)(u.z&0xffff)); av[5]=b2f((unsigned short)(u.z>>16));
            av[6]=b2f((unsigned short)(u.w&0xffff)); av[7]=b2f((unsigned short)(u.w>>16));
            union { unsigned short u[8]; uint4 v; } ob;
            const float* xr = x + (size_t)gr * 127;
            #pragma unroll
            for (int j = 0; j < 8; ++j) {
                int f = c0 + j;
                float xval = (f < 127) ? xr[f] : t[gr];
                ob.u[j] = f2b(xval + av[j]);
            }
            *(uint4*)&U[idx128(r, c0)] = ob.v;
        }
    }
    __syncthreads();

    f32x4 acc[4][4];
    const f32x4 zero = {0.f, 0.f, 0.f, 0.f};

    // ======== stage 1: h1 = relu(h_in @ W1 + b1); U := h1 ========
    #pragma unroll
    for (int nt = 0; nt < 4; ++nt)
        #pragma unroll
        for (int rt = 0; rt < 4; ++rt) acc[rt][nt] = zero;

    for (int kt = 0; kt < 4; ++kt) {
        bf16x8 a[4];
        #pragma unroll
        for (int rt = 0; rt < 4; ++rt)
            a[rt] = *(const bf16x8*)&U[idx128(rt * 16 + lr, kt * 32 + lk)];
        #pragma unroll
        for (int nt = 0; nt < 4; ++nt) {
            size_t bofs = (size_t)((kt * 16 + ntg0 + nt) * 64 + lane) * 8;
            bf16x8 bh = *(const bf16x8*)(W1h + bofs);
            bf16x8 bl = *(const bf16x8*)(W1l + bofs);
            #pragma unroll
            for (int rt = 0; rt < 4; ++rt) {
                acc[rt][nt] = __builtin_amdgcn_mfma_f32_16x16x32_bf16(a[rt], bl, acc[rt][nt], 0, 0, 0);
                acc[rt][nt] = __builtin_amdgcn_mfma_f32_16x16x32_bf16(a[rt], bh, acc[rt][nt], 0, 0, 0);
            }
        }
    }
    __syncthreads();    // all h_in reads complete before overwrite
    #pragma unroll
    for (int nt = 0; nt < 4; ++nt) {
        int col = (ntg0 + nt) * 16 + lr;
        float bv = b1[col];
        #pragma unroll
        for (int rt = 0; rt < 4; ++rt)
            #pragma unroll
            for (int r4 = 0; r4 < 4; ++r4)
                U[idx256(rt * 16 + rbase + r4, col)] = f2b(fmaxf(acc[rt][nt][r4] + bv, 0.f));
    }
    __syncthreads();

    // ======== stage 2: h = tanh(relu(h1 @ W2 + b2)); U := h ========
    #pragma unroll
    for (int nt = 0; nt < 4; ++nt)
        #pragma unroll
        for (int rt = 0; rt < 4; ++rt) acc[rt][nt] = zero;

    for (int kt = 0; kt < 8; ++kt) {
        bf16x8 a[4];
        #pragma unroll
        for (int rt = 0; rt < 4; ++rt)
            a[rt] = *(const bf16x8*)&U[idx256(rt * 16 + lr, kt * 32 + lk)];
        #pragma unroll
        for (int nt = 0; nt < 4; ++nt) {
            size_t bofs = (size_t)((kt * 16 + ntg0 + nt) * 64 + lane) * 8;
            bf16x8 bh = *(const bf16x8*)(W2h + bofs);
            bf16x8 bl = *(const bf16x8*)(W2l + bofs);
            #pragma unroll
            for (int rt = 0; rt < 4; ++rt) {
                acc[rt][nt] = __builtin_amdgcn_mfma_f32_16x16x32_bf16(a[rt], bl, acc[rt][nt], 0, 0, 0);
                acc[rt][nt] = __builtin_amdgcn_mfma_f32_16x16x32_bf16(a[rt], bh, acc[rt][nt], 0, 0, 0);
            }
        }
    }
    __syncthreads();    // all h1 reads complete
    #pragma unroll
    for (int nt = 0; nt < 4; ++nt) {
        int col = (ntg0 + nt) * 16 + lr;
        float bv = b2[col];
        #pragma unroll
        for (int rt = 0; rt < 4; ++rt)
            #pragma unroll
            for (int r4 = 0; r4 < 4; ++r4) {
                float v = fmaxf(acc[rt][nt][r4] + bv, 0.f);   // relu∘tanh == tanh∘relu
                float e = __expf(-2.f * v);
                U[idx256(rt * 16 + rbase + r4, col)] = f2b((1.f - e) / (1.f + e));
            }
    }
    __syncthreads();

    // ======== stage 3: p1 = lrelu([h | x_in] @ P1 + pb1); U := p1 ========
    #pragma unroll
    for (int nt = 0; nt < 4; ++nt)
        #pragma unroll
        for (int rt = 0; rt < 4; ++rt) acc[rt][nt] = zero;

    for (int kt = 0; kt < 12; ++kt) {
        bf16x8 a[4];
        if (kt < 8) {
            #pragma unroll
            for (int rt = 0; rt < 4; ++rt)
                a[rt] = *(const bf16x8*)&U[idx256(rt * 16 + lr, kt * 32 + lk)];
        } else if (FUSED) {
            #pragma unroll
            for (int rt = 0; rt < 4; ++rt) {
                int r = row0 + rt * 16 + lr; if (r >= M) r = M - 1;
                a[rt] = *(const bf16x8*)(xb + (size_t)r * 128 + (kt - 8) * 32 + lk);
            }
        } else {
            #pragma unroll
            for (int rt = 0; rt < 4; ++rt) {
                int r = row0 + rt * 16 + lr; if (r >= M) r = M - 1;
                int c0 = (kt - 8) * 32 + lk;
                const float* xr = x + (size_t)r * 127;
                union { unsigned short u[8]; bf16x8 v; } au;
                #pragma unroll
                for (int j = 0; j < 8; ++j) {
                    int f = c0 + j;
                    au.u[j] = f2b((f < 127) ? xr[f] : t[r]);
                }
                a[rt] = au.v;
            }
        }
        #pragma unroll
        for (int nt = 0; nt < 4; ++nt) {
            size_t bofs = (size_t)((kt * 16 + ntg0 + nt) * 64 + lane) * 8;
            bf16x8 bh = *(const bf16x8*)(P1h + bofs);
            bf16x8 bl = *(const bf16x8*)(P1l + bofs);
            #pragma unroll
            for (int rt = 0; rt < 4; ++rt) {
                acc[rt][nt] = __builtin_amdgcn_mfma_f32_16x16x32_bf16(a[rt], bl, acc[rt][nt], 0, 0, 0);
                acc[rt][nt] = __builtin_amdgcn_mfma_f32_16x16x32_bf16(a[rt], bh, acc[rt][nt], 0, 0, 0);
            }
        }
    }
    __syncthreads();    // all h reads complete
    #pragma unroll
    for (int nt = 0; nt < 4; ++nt) {
        int col = (ntg0 + nt) * 16 + lr;
        float bv = pb1[col];
        #pragma unroll
        for (int rt = 0; rt < 4; ++rt)
            #pragma unroll
            for (int r4 = 0; r4 < 4; ++r4) {
                float v = acc[rt][nt][r4] + bv;
                U[idx256(rt * 16 + rbase + r4, col)] = f2b((v > 0.f) ? v : 0.2f * v);
            }
    }
    __syncthreads();

    // ======== stage 4: p2 = lrelu(p1 @ P2 + pb2); pred = p2 . P3 + pb3 ========
    #pragma unroll
    for (int nt = 0; nt < 4; ++nt)
        #pragma unroll
        for (int rt = 0; rt < 4; ++rt) acc[rt][nt] = zero;

    for (int kt = 0; kt < 8; ++kt) {
        bf16x8 a[4];
        #pragma unroll
        for (int rt = 0; rt < 4; ++rt)
            a[rt] = *(const bf16x8*)&U[idx256(rt * 16 + lr, kt * 32 + lk)];
        #pragma unroll
        for (int nt = 0; nt < 4; ++nt) {
            size_t bofs = (size_t)((kt * 16 + ntg0 + nt) * 64 + lane) * 8;
            bf16x8 bh = *(const bf16x8*)(P2h + bofs);
            bf16x8 bl = *(const bf16x8*)(P2l + bofs);
            #pragma unroll
            for (int rt = 0; rt < 4; ++rt) {
                acc[rt][nt] = __builtin_amdgcn_mfma_f32_16x16x32_bf16(a[rt], bl, acc[rt][nt], 0, 0, 0);
                acc[rt][nt] = __builtin_amdgcn_mfma_f32_16x16x32_bf16(a[rt], bh, acc[rt][nt], 0, 0, 0);
            }
        }
    }
    float part[4][4];
    #pragma unroll
    for (int rt = 0; rt < 4; ++rt)
        #pragma unroll
        for (int r4 = 0; r4 < 4; ++r4) part[rt][r4] = 0.f;
    #pragma unroll
    for (int nt = 0; nt < 4; ++nt) {
        int col = (ntg0 + nt) * 16 + lr;
        float bv = pb2[col];
        float p3 = P3[col];
        #pragma unroll
        for (int rt = 0; rt < 4; ++rt)
            #pragma unroll
            for (int r4 = 0; r4 < 4; ++r4) {
                float v = acc[rt][nt][r4] + bv;
                v = (v > 0.f) ? v : 0.2f * v;
                part[rt][r4] += v * p3;
            }
    }
    #pragma unroll
    for (int rt = 0; rt < 4; ++rt)
        #pragma unroll
        for (int r4 = 0; r4 < 4; ++r4) {
            float s = part[rt][r4];
            s += __shfl_xor(s, 1);
            s += __shfl_xor(s, 2);
            s += __shfl_xor(s, 4);
            s += __shfl_xor(s, 8);
            if (lr == 0) red[wave * 64 + rt * 16 + rbase + r4] = s;
        }
    __syncthreads();
    if (threadIdx.x < 64) {
        int row = row0 + threadIdx.x;
        if (row < M) {
            float s = red[threadIdx.x] + red[64 + threadIdx.x]
                    + red[128 + threadIdx.x] + red[192 + threadIdx.x] + pb3[0];
            out[M + row] = s;
        }
    }
}

extern "C" void kernel_launch(void* const* d_in, const int* in_sizes, int n_in,
                              void* d_out, int out_size, void* d_ws, size_t ws_size,
                              hipStream_t stream)
{
    const int M = in_sizes[1];                 // 50000
    const int E = in_sizes[3] / 2;             // 800000
    const float* x   = (const float*)d_in[0];
    const float* t   = (const float*)d_in[1];
    const int*   ei  = (const int*)d_in[3];
    const float* W1  = (const float*)d_in[4];
    const float* b1  = (const float*)d_in[5];
    const float* W2  = (const float*)d_in[6];
    const float* b2  = (const float*)d_in[7];
    const float* P1  = (const float*)d_in[8];
    const float* pb1 = (const float*)d_in[9];
    const float* P2  = (const float*)d_in[10];
    const float* pb2 = (const float*)d_in[11];
    const float* P3  = (const float*)d_in[12];
    const float* pb3 = (const float*)d_in[13];
    float* out = (float*)d_out;

    // fused tier: xb 12.8 + weights 1 + sorted 3.2 + csr 0.6 ~ 17.7 MB
    const size_t xbB   = (size_t)M * 128 * 2;
    const size_t wB    = (size_t)(128 + 256 + 384 + 256) * 256 * 2 * 2;   // 1 MB
    const size_t sortB = (size_t)E * 4;
    const size_t csrB  = (size_t)(3 * M + 2) * 4;
    const size_t aggBF = (size_t)M * 128 * 2;
    char* ws = (char*)d_ws;
    auto al = [](size_t v) { return (v + 255) & ~(size_t)255; };

    bool fused = ws_size >= al(xbB) + al(wB) + al(sortB) + al(csrB) + 4096;

    int gblocks = (M + 63) / 64;
    int pxb = (M * 128 + 255) / 256;
    int eblocks = (E + 255) / 256;

    if (fused) {
        unsigned short* xb  = (unsigned short*)ws;
        unsigned short* W1h = (unsigned short*)(ws + al(xbB));
        unsigned short* W1l = W1h + 128 * 256;
        unsigned short* W2h = W1l + 128 * 256;
        unsigned short* W2l = W2h + 256 * 256;
        unsigned short* P1h = W2l + 256 * 256;
        unsigned short* P1l = P1h + 384 * 256;
        unsigned short* P2h = P1l + 384 * 256;
        unsigned short* P2l = P2h + 256 * 256;
        int* sorted = (int*)((char*)(P2l + 256 * 256));
        int* count  = sorted + E;
        int* start  = count + M;        // M+1 entries
        int* cursor = start + M + 1;

        pack_kernel<<<128, 256, 0, stream>>>(W1, W1h, W1l, 128);
        pack_kernel<<<256, 256, 0, stream>>>(W2, W2h, W2l, 256);
        pack_kernel<<<384, 256, 0, stream>>>(P1, P1h, P1l, 384);
        pack_kernel<<<256, 256, 0, stream>>>(P2, P2h, P2l, 256);

        prep_xb_kernel<<<pxb, 256, 0, stream>>>(x, t, xb, out, count, M);
        hist_node_kernel<<<eblocks, 256, 0, stream>>>(ei, count, E, M);
        scan_node_kernel<<<1, 1024, 0, stream>>>(count, start, cursor, M);
        reorder_csr_kernel<<<eblocks, 256, 0, stream>>>(ei, cursor, sorted, E, M);
        mega_kernel<true><<<gblocks, 256, 0, stream>>>(
            x, t, xb, nullptr, start, sorted,
            W1h, W1l, b1, W2h, W2l, b2,
            P1h, P1l, pb1, P2h, P2l, pb2, P3, pb3, out, M);
    } else {
        unsigned short* agg = (unsigned short*)ws;
        unsigned short* W1h = (unsigned short*)(ws + al(aggBF));
        unsigned short* W1l = W1h + 128 * 256;
        unsigned short* W2h = W1l + 128 * 256;
        unsigned short* W2l = W2h + 256 * 256;
        unsigned short* P1h = W2l + 256 * 256;
        unsigned short* P1l = P1h + 384 * 256;
        unsigned short* P2h = P1l + 384 * 256;
        unsigned short* P2l = P2h + 256 * 256;

        pack_kernel<<<128, 256, 0, stream>>>(W1, W1h, W1l, 128);
        pack_kernel<<<256, 256, 0, stream>>>(W2, W2h, W2l, 256);
        pack_kernel<<<384, 256, 0, stream>>>(P1, P1h, P1l, 384);
        pack_kernel<<<256, 256, 0, stream>>>(P2, P2h, P2l, 256);

        prep_kernel<<<pxb, 256, 0, stream>>>(agg, out, M);
        scatter_kernel<<<(E + 7) / 8, 256, 0, stream>>>(ei, x, t, agg, E, M);
        mega_kernel<false><<<gblocks, 256, 0, stream>>>(
            x, t, nullptr, agg, nullptr, nullptr,
            W1h, W1l, b1, W2h, W2l, b2,
            P1h, P1l, pb1, P2h, P2l, pb2, P3, pb3, out, M);
    }
}

// Round 12
// 472.054 us; speedup vs baseline: 1.1934x; 1.1934x over previous
//
#include <hip/hip_runtime.h>
#include <hip/hip_bf16.h>

// ---------- bf16 helpers (raw ushort storage) ----------
__device__ __forceinline__ float b2f(unsigned short u) {
    union { float f; unsigned int i; } v; v.i = ((unsigned int)u) << 16; return v.f;
}
__device__ __forceinline__ unsigned short f2b(float f) {
    union { float f; unsigned int i; } v; v.f = f;
    unsigned int i = v.i;
    return (unsigned short)((i + 0x7FFFu + ((i >> 16) & 1u)) >> 16);   // RNE
}

typedef __bf16 bf16x8 __attribute__((ext_vector_type(8)));
typedef float  f32x4  __attribute__((ext_vector_type(4)));

#define MROWS 32   // mega rows/block; acc[2][4] (32 regs) -> no VGPR cliff, no bounds

// 256-col LDS tile: row stride 256, XOR-16B swizzle
__device__ __forceinline__ int idx256(int r, int c) {
    return r * 256 + (((c >> 3) ^ (r & 31)) << 3) + (c & 7);
}
// 128-col LDS tile
__device__ __forceinline__ int idx128(int r, int c) {
    return r * 128 + ((((c >> 3) ^ r) & 15) << 3) + (c & 7);
}

// ---------- prep: xb[M][128] = bf16([x | t]); out[t_pred] = 0; count = 0 -----
__global__ __launch_bounds__(256) void prep_xb_kernel(
    const float* __restrict__ x, const float* __restrict__ t,
    unsigned short* __restrict__ xb, float* __restrict__ out,
    int* __restrict__ count, int M)
{
    int idx = blockIdx.x * 256 + threadIdx.x;          // over M*128
    if (idx < M * 128) {
        int i = idx >> 7, j = idx & 127;
        xb[idx] = f2b((j < 127) ? x[(size_t)i * 127 + j] : t[i]);
    }
    if (idx < M) { out[idx] = 0.0f; count[idx] = 0; }
}

// ---------- fallback prep: agg = 0; out[t_pred] = 0 ----------
__global__ __launch_bounds__(256) void prep_kernel(unsigned short* __restrict__ agg,
                                                   float* __restrict__ out, int M)
{
    int idx = blockIdx.x * 256 + threadIdx.x;
    if (idx < M * 128) agg[idx] = 0;
    if (idx < M) out[idx] = 0.0f;
}

// ---------- fallback scatter: bf16 packed global atomics ----------
__global__ __launch_bounds__(256) void scatter_kernel(
    const int* __restrict__ ei, const float* __restrict__ x,
    const float* __restrict__ t, unsigned short* __restrict__ agg, int E, int M)
{
    int e = blockIdx.x * 8 + (threadIdx.x >> 5);
    if (e >= E) return;
    int lane = threadIdx.x & 31;
    int s = ei[e];
    int d = ei[E + e];
    if ((unsigned)s >= (unsigned)M || (unsigned)d >= (unsigned)M) return;
    int f0 = lane * 4;
    const float* xr = x + (size_t)s * 127;
    float v0 = xr[f0];
    float v1 = xr[f0 + 1];
    float v2 = xr[f0 + 2];
    float v3 = (f0 + 3 < 127) ? xr[f0 + 3] : t[s];
    __hip_bfloat162* dp = (__hip_bfloat162*)(agg + (size_t)d * 128 + f0);
    __hip_bfloat162 a; a.x = __float2bfloat16(v0); a.y = __float2bfloat16(v1);
    __hip_bfloat162 b; b.x = __float2bfloat16(v2); b.y = __float2bfloat16(v3);
    unsafeAtomicAdd(dp,     a);
    unsafeAtomicAdd(dp + 1, b);
}

// ---------- S1: per-node in-degree histogram ----------
__global__ __launch_bounds__(256) void hist_node_kernel(
    const int* __restrict__ ei, int* __restrict__ count, int E, int M)
{
    int e = blockIdx.x * 256 + threadIdx.x;
    if (e >= E) return;
    int s = ei[e];
    int d = ei[E + e];
    if ((unsigned)s < (unsigned)M && (unsigned)d < (unsigned)M)
        atomicAdd(&count[d], 1);
}

// ---------- S2: exclusive scan over M node counts (1 block, 1024 thr) --------
__global__ __launch_bounds__(1024) void scan_node_kernel(
    const int* __restrict__ count, int* __restrict__ start,
    int* __restrict__ cursor, int M)
{
    __shared__ int tsum[1024];
    int tid = threadIdx.x;
    int chunk = (M + 1023) >> 10;
    int lo = tid * chunk;
    int hi = lo + chunk; if (hi > M) hi = M;
    int s = 0;
    for (int i = lo; i < hi; ++i) s += count[i];
    tsum[tid] = s;
    __syncthreads();
    for (int off = 1; off < 1024; off <<= 1) {
        int a = (tid >= off) ? tsum[tid - off] : 0;
        __syncthreads();
        tsum[tid] += a;
        __syncthreads();
    }
    int run = tsum[tid] - s;
    for (int i = lo; i < hi; ++i) {
        start[i] = run;
        cursor[i] = run;
        run += count[i];
    }
    if (tid == 1023) start[M] = run;
}

// ---------- S3: reorder srcs into dst-sorted CSR order ----------
__global__ __launch_bounds__(256) void reorder_csr_kernel(
    const int* __restrict__ ei, int* __restrict__ cursor,
    int* __restrict__ sorted, int E, int M)
{
    int e = blockIdx.x * 256 + threadIdx.x;
    if (e >= E) return;
    int s = ei[e];
    int d = ei[E + e];
    if ((unsigned)s < (unsigned)M && (unsigned)d < (unsigned)M) {
        int slot = atomicAdd(&cursor[d], 1);
        sorted[slot] = s;
    }
}

// ---------- S4: CSR gather — half-wave per node, 8-edge batches, no atomics --
#define GU 8
template<bool F32AGG>
__global__ __launch_bounds__(256) void gather_csr_kernel(
    const unsigned short* __restrict__ xb, const int* __restrict__ sorted,
    const int* __restrict__ start, void* __restrict__ agg, int M)
{
    int node = blockIdx.x * 8 + (threadIdx.x >> 5);
    if (node >= M) return;
    int lane = threadIdx.x & 31;
    int s0 = start[node], s1 = start[node + 1];
    float a0 = 0.f, a1 = 0.f, a2 = 0.f, a3 = 0.f;
    for (int base = s0; base < s1; base += GU) {
        int last = s1 - 1;
        int idxe[GU];
        #pragma unroll
        for (int g = 0; g < GU; ++g) {
            int i = base + g;
            idxe[g] = (i < s1) ? i : last;       // clamp (loads harmless, adds masked)
        }
        uint2 rv[GU];
        #pragma unroll
        for (int g = 0; g < GU; ++g) {
            int src = sorted[idxe[g]];
            rv[g] = *(const uint2*)(xb + (size_t)src * 128 + lane * 4);
        }
        #pragma unroll
        for (int g = 0; g < GU; ++g) {
            if (base + g < s1) {
                a0 += b2f((unsigned short)(rv[g].x & 0xffff));
                a1 += b2f((unsigned short)(rv[g].x >> 16));
                a2 += b2f((unsigned short)(rv[g].y & 0xffff));
                a3 += b2f((unsigned short)(rv[g].y >> 16));
            }
        }
    }
    size_t o = (size_t)node * 128 + lane * 4;
    if (F32AGG) {
        float4 w; w.x = a0; w.y = a1; w.z = a2; w.w = a3;
        *(float4*)((float*)agg + o) = w;
    } else {
        uint2 w;
        w.x = (unsigned)f2b(a0) | ((unsigned)f2b(a1) << 16);
        w.y = (unsigned)f2b(a2) | ((unsigned)f2b(a3) << 16);
        *(uint2*)((unsigned short*)agg + o) = w;
    }
}

// ---------- pack fp32 weight B[K x 256] -> hi/lo bf16 planes, MFMA B order ----
__global__ __launch_bounds__(256) void pack_kernel(
    const float* __restrict__ B, unsigned short* __restrict__ Bhi,
    unsigned short* __restrict__ Blo, int K)
{
    int idx = blockIdx.x * 256 + threadIdx.x;
    if (idx >= K * 256) return;
    int j    = idx & 7;
    int lane = (idx >> 3) & 63;
    int nt   = (idx >> 9) & 15;
    int kt   = idx >> 13;
    int k = kt * 32 + ((lane >> 4) * 8) + j;
    int n = nt * 16 + (lane & 15);
    float w = B[k * 256 + n];
    unsigned short hi = f2b(w);
    Bhi[idx] = hi;
    Blo[idx] = f2b(w - b2f(hi));
}

// ---------- mega: 4 GEMMs + final dot, 32-row blocks, single 16 KB LDS -------
// acc[2][4] (32 regs) keeps natural VGPR demand ~110-130 -> 3-4 waves/SIMD.
// NO __launch_bounds__ min-waves arg: R9 (256,4)->64 VGPR/144 MB spill,
// R11 (256,3)->84 VGPR/70 MB spill. Let the allocator breathe.
template<bool BF16AGG>
__global__ __launch_bounds__(256) void mega_kernel(
    const float* __restrict__ x, const float* __restrict__ t,
    const unsigned short* __restrict__ xb,
    const void* __restrict__ aggv,
    const unsigned short* __restrict__ W1h, const unsigned short* __restrict__ W1l,
    const float* __restrict__ b1,
    const unsigned short* __restrict__ W2h, const unsigned short* __restrict__ W2l,
    const float* __restrict__ b2,
    const unsigned short* __restrict__ P1h, const unsigned short* __restrict__ P1l,
    const float* __restrict__ pb1,
    const unsigned short* __restrict__ P2h, const unsigned short* __restrict__ P2l,
    const float* __restrict__ pb2,
    const float* __restrict__ P3, const float* __restrict__ pb3,
    float* __restrict__ out, int M)
{
    __shared__ unsigned short U[MROWS * 256];   // 16 KB: h_in -> h1 -> h -> p1
    __shared__ float red[4 * MROWS];            // 512 B

    const int wave = threadIdx.x >> 6;
    const int lane = threadIdx.x & 63;
    const int lr   = lane & 15;
    const int quad = lane >> 4;
    const int lk   = quad * 8;
    const int rbase = quad * 4;
    const int row0 = blockIdx.x * MROWS;
    const int ntg0 = wave * 4;

    // ---- U[idx128] = bf16(x_in + agg): 32 rows x 128 cols ----
    {
        int r = threadIdx.x >> 3;            // 0..31
        int q = threadIdx.x & 7;             // 0..7, 16 cols each
        int gr = row0 + r; if (gr >= M) gr = M - 1;
        #pragma unroll
        for (int c8 = 0; c8 < 2; ++c8) {
            int c0 = q * 16 + c8 * 8;
            float av[8];
            if (BF16AGG) {
                const unsigned short* ar = (const unsigned short*)aggv + (size_t)gr * 128 + c0;
                uint4 u = *(const uint4*)ar;
                av[0]=b2f((unsigned short)(u.x&0xffff)); av[1]=b2f((unsigned short)(u.x>>16));
                av[2]=b2f((unsigned short)(u.y&0xffff)); av[3]=b2f((unsigned short)(u.y>>16));
                av[4]=b2f((unsigned short)(u.z&0xffff)); av[5]=b2f((unsigned short)(u.z>>16));
                av[6]=b2f((unsigned short)(u.w&0xffff)); av[7]=b2f((unsigned short)(u.w>>16));
            } else {
                const float* ar = (const float*)aggv + (size_t)gr * 128 + c0;
                float4 g0 = *(const float4*)ar, g1 = *(const float4*)(ar + 4);
                av[0]=g0.x; av[1]=g0.y; av[2]=g0.z; av[3]=g0.w;
                av[4]=g1.x; av[5]=g1.y; av[6]=g1.z; av[7]=g1.w;
            }
            union { unsigned short u[8]; uint4 v; } ob;
            if (xb) {
                union { uint4 v; unsigned short u[8]; } xv;
                xv.v = *(const uint4*)(xb + (size_t)gr * 128 + c0);
                #pragma unroll
                for (int j = 0; j < 8; ++j) ob.u[j] = f2b(b2f(xv.u[j]) + av[j]);
            } else {
                const float* xr = x + (size_t)gr * 127;
                #pragma unroll
                for (int j = 0; j < 8; ++j) {
                    int f = c0 + j;
                    float xval = (f < 127) ? xr[f] : t[gr];
                    ob.u[j] = f2b(xval + av[j]);
                }
            }
            *(uint4*)&U[idx128(r, c0)] = ob.v;
        }
    }
    __syncthreads();

    f32x4 acc[2][4];
    const f32x4 zero = {0.f, 0.f, 0.f, 0.f};

    // ======== stage 1: h1 = relu(h_in @ W1 + b1); U := h1 ========
    #pragma unroll
    for (int nt = 0; nt < 4; ++nt)
        #pragma unroll
        for (int rt = 0; rt < 2; ++rt) acc[rt][nt] = zero;

    for (int kt = 0; kt < 4; ++kt) {
        bf16x8 a[2];
        #pragma unroll
        for (int rt = 0; rt < 2; ++rt)
            a[rt] = *(const bf16x8*)&U[idx128(rt * 16 + lr, kt * 32 + lk)];
        #pragma unroll
        for (int nt = 0; nt < 4; ++nt) {
            size_t bofs = (size_t)((kt * 16 + ntg0 + nt) * 64 + lane) * 8;
            bf16x8 bh = *(const bf16x8*)(W1h + bofs);
            bf16x8 bl = *(const bf16x8*)(W1l + bofs);
            #pragma unroll
            for (int rt = 0; rt < 2; ++rt) {
                acc[rt][nt] = __builtin_amdgcn_mfma_f32_16x16x32_bf16(a[rt], bl, acc[rt][nt], 0, 0, 0);
                acc[rt][nt] = __builtin_amdgcn_mfma_f32_16x16x32_bf16(a[rt], bh, acc[rt][nt], 0, 0, 0);
            }
        }
    }
    __syncthreads();    // all h_in reads complete before overwrite
    #pragma unroll
    for (int nt = 0; nt < 4; ++nt) {
        int col = (ntg0 + nt) * 16 + lr;
        float bv = b1[col];
        #pragma unroll
        for (int rt = 0; rt < 2; ++rt)
            #pragma unroll
            for (int r4 = 0; r4 < 4; ++r4)
                U[idx256(rt * 16 + rbase + r4, col)] = f2b(fmaxf(acc[rt][nt][r4] + bv, 0.f));
    }
    __syncthreads();

    // ======== stage 2: h = tanh(relu(h1 @ W2 + b2)); U := h ========
    #pragma unroll
    for (int nt = 0; nt < 4; ++nt)
        #pragma unroll
        for (int rt = 0; rt < 2; ++rt) acc[rt][nt] = zero;

    for (int kt = 0; kt < 8; ++kt) {
        bf16x8 a[2];
        #pragma unroll
        for (int rt = 0; rt < 2; ++rt)
            a[rt] = *(const bf16x8*)&U[idx256(rt * 16 + lr, kt * 32 + lk)];
        #pragma unroll
        for (int nt = 0; nt < 4; ++nt) {
            size_t bofs = (size_t)((kt * 16 + ntg0 + nt) * 64 + lane) * 8;
            bf16x8 bh = *(const bf16x8*)(W2h + bofs);
            bf16x8 bl = *(const bf16x8*)(W2l + bofs);
            #pragma unroll
            for (int rt = 0; rt < 2; ++rt) {
                acc[rt][nt] = __builtin_amdgcn_mfma_f32_16x16x32_bf16(a[rt], bl, acc[rt][nt], 0, 0, 0);
                acc[rt][nt] = __builtin_amdgcn_mfma_f32_16x16x32_bf16(a[rt], bh, acc[rt][nt], 0, 0, 0);
            }
        }
    }
    __syncthreads();    // all h1 reads complete
    #pragma unroll
    for (int nt = 0; nt < 4; ++nt) {
        int col = (ntg0 + nt) * 16 + lr;
        float bv = b2[col];
        #pragma unroll
        for (int rt = 0; rt < 2; ++rt)
            #pragma unroll
            for (int r4 = 0; r4 < 4; ++r4) {
                float v = fmaxf(acc[rt][nt][r4] + bv, 0.f);   // relu∘tanh == tanh∘relu
                float e = __expf(-2.f * v);
                U[idx256(rt * 16 + rbase + r4, col)] = f2b((1.f - e) / (1.f + e));
            }
    }
    __syncthreads();

    // ======== stage 3: p1 = lrelu([h | x_in] @ P1 + pb1); U := p1 ========
    #pragma unroll
    for (int nt = 0; nt < 4; ++nt)
        #pragma unroll
        for (int rt = 0; rt < 2; ++rt) acc[rt][nt] = zero;

    for (int kt = 0; kt < 12; ++kt) {
        bf16x8 a[2];
        if (kt < 8) {
            #pragma unroll
            for (int rt = 0; rt < 2; ++rt)
                a[rt] = *(const bf16x8*)&U[idx256(rt * 16 + lr, kt * 32 + lk)];
        } else if (xb) {
            #pragma unroll
            for (int rt = 0; rt < 2; ++rt) {
                int r = row0 + rt * 16 + lr; if (r >= M) r = M - 1;
                a[rt] = *(const bf16x8*)(xb + (size_t)r * 128 + (kt - 8) * 32 + lk);
            }
        } else {
            #pragma unroll
            for (int rt = 0; rt < 2; ++rt) {
                int r = row0 + rt * 16 + lr; if (r >= M) r = M - 1;
                int c0 = (kt - 8) * 32 + lk;
                const float* xr = x + (size_t)r * 127;
                union { unsigned short u[8]; bf16x8 v; } au;
                #pragma unroll
                for (int j = 0; j < 8; ++j) {
                    int f = c0 + j;
                    au.u[j] = f2b((f < 127) ? xr[f] : t[r]);
                }
                a[rt] = au.v;
            }
        }
        #pragma unroll
        for (int nt = 0; nt < 4; ++nt) {
            size_t bofs = (size_t)((kt * 16 + ntg0 + nt) * 64 + lane) * 8;
            bf16x8 bh = *(const bf16x8*)(P1h + bofs);
            bf16x8 bl = *(const bf16x8*)(P1l + bofs);
            #pragma unroll
            for (int rt = 0; rt < 2; ++rt) {
                acc[rt][nt] = __builtin_amdgcn_mfma_f32_16x16x32_bf16(a[rt], bl, acc[rt][nt], 0, 0, 0);
                acc[rt][nt] = __builtin_amdgcn_mfma_f32_16x16x32_bf16(a[rt], bh, acc[rt][nt], 0, 0, 0);
            }
        }
    }
    __syncthreads();    // all h reads complete
    #pragma unroll
    for (int nt = 0; nt < 4; ++nt) {
        int col = (ntg0 + nt) * 16 + lr;
        float bv = pb1[col];
        #pragma unroll
        for (int rt = 0; rt < 2; ++rt)
            #pragma unroll
            for (int r4 = 0; r4 < 4; ++r4) {
                float v = acc[rt][nt][r4] + bv;
                U[idx256(rt * 16 + rbase + r4, col)] = f2b((v > 0.f) ? v : 0.2f * v);
            }
    }
    __syncthreads();

    // ======== stage 4: p2 = lrelu(p1 @ P2 + pb2); pred = p2 . P3 + pb3 ========
    #pragma unroll
    for (int nt = 0; nt < 4; ++nt)
        #pragma unroll
        for (int rt = 0; rt < 2; ++rt) acc[rt][nt] = zero;

    for (int kt = 0; kt < 8; ++kt) {
        bf16x8 a[2];
        #pragma unroll
        for (int rt = 0; rt < 2; ++rt)
            a[rt] = *(const bf16x8*)&U[idx256(rt * 16 + lr, kt * 32 + lk)];
        #pragma unroll
        for (int nt = 0; nt < 4; ++nt) {
            size_t bofs = (size_t)((kt * 16 + ntg0 + nt) * 64 + lane) * 8;
            bf16x8 bh = *(const bf16x8*)(P2h + bofs);
            bf16x8 bl = *(const bf16x8*)(P2l + bofs);
            #pragma unroll
            for (int rt = 0; rt < 2; ++rt) {
                acc[rt][nt] = __builtin_amdgcn_mfma_f32_16x16x32_bf16(a[rt], bl, acc[rt][nt], 0, 0, 0);
                acc[rt][nt] = __builtin_amdgcn_mfma_f32_16x16x32_bf16(a[rt], bh, acc[rt][nt], 0, 0, 0);
            }
        }
    }
    float part[2][4];
    #pragma unroll
    for (int rt = 0; rt < 2; ++rt)
        #pragma unroll
        for (int r4 = 0; r4 < 4; ++r4) part[rt][r4] = 0.f;
    #pragma unroll
    for (int nt = 0; nt < 4; ++nt) {
        int col = (ntg0 + nt) * 16 + lr;
        float bv = pb2[col];
        float p3 = P3[col];
        #pragma unroll
        for (int rt = 0; rt < 2; ++rt)
            #pragma unroll
            for (int r4 = 0; r4 < 4; ++r4) {
                float v = acc[rt][nt][r4] + bv;
                v = (v > 0.f) ? v : 0.2f * v;
                part[rt][r4] += v * p3;
            }
    }
    #pragma unroll
    for (int rt = 0; rt < 2; ++rt)
        #pragma unroll
        for (int r4 = 0; r4 < 4; ++r4) {
            float s = part[rt][r4];
            s += __shfl_xor(s, 1);
            s += __shfl_xor(s, 2);
            s += __shfl_xor(s, 4);
            s += __shfl_xor(s, 8);
            if (lr == 0) red[wave * MROWS + rt * 16 + rbase + r4] = s;
        }
    __syncthreads();
    if (threadIdx.x < MROWS) {
        int row = row0 + threadIdx.x;
        if (row < M) {
            float s = red[threadIdx.x] + red[MROWS + threadIdx.x]
                    + red[2 * MROWS + threadIdx.x] + red[3 * MROWS + threadIdx.x] + pb3[0];
            out[M + row] = s;
        }
    }
}

extern "C" void kernel_launch(void* const* d_in, const int* in_sizes, int n_in,
                              void* d_out, int out_size, void* d_ws, size_t ws_size,
                              hipStream_t stream)
{
    const int M = in_sizes[1];                 // 50000
    const int E = in_sizes[3] / 2;             // 800000
    const float* x   = (const float*)d_in[0];
    const float* t   = (const float*)d_in[1];
    const int*   ei  = (const int*)d_in[3];
    const float* W1  = (const float*)d_in[4];
    const float* b1  = (const float*)d_in[5];
    const float* W2  = (const float*)d_in[6];
    const float* b2  = (const float*)d_in[7];
    const float* P1  = (const float*)d_in[8];
    const float* pb1 = (const float*)d_in[9];
    const float* P2  = (const float*)d_in[10];
    const float* pb2 = (const float*)d_in[11];
    const float* P3  = (const float*)d_in[12];
    const float* pb3 = (const float*)d_in[13];
    float* out = (float*)d_out;

    const size_t aggF32 = (size_t)M * 128 * 4;
    const size_t aggBF  = (size_t)M * 128 * 2;
    const size_t xbB    = (size_t)M * 128 * 2;
    const size_t wB     = (size_t)(128 + 256 + 384 + 256) * 256 * 2 * 2;   // 1 MB
    const size_t sortB  = (size_t)E * 4;
    const size_t csrB   = (size_t)(3 * M + 2) * 4;
    char* ws = (char*)d_ws;
    auto al = [](size_t v) { return (v + 255) & ~(size_t)255; };

    bool tierA = ws_size >= al(aggF32) + al(xbB) + al(wB) + al(sortB) + al(csrB) + 4096;
    bool tierB = ws_size >= al(aggBF)  + al(xbB) + al(wB) + al(sortB) + al(csrB) + 4096;

    size_t aggBytes = tierA ? aggF32 : aggBF;
    void* agg = (void*)ws;
    unsigned short* xb = (unsigned short*)(ws + al(aggBytes));
    unsigned short* W1h = (unsigned short*)((char*)xb + al(xbB));
    unsigned short* W1l = W1h + 128 * 256;
    unsigned short* W2h = W1l + 128 * 256;
    unsigned short* W2l = W2h + 256 * 256;
    unsigned short* P1h = W2l + 256 * 256;
    unsigned short* P1l = P1h + 384 * 256;
    unsigned short* P2h = P1l + 384 * 256;
    unsigned short* P2l = P2h + 256 * 256;
    int* sorted = (int*)(P2l + 256 * 256);
    int* count  = sorted + E;
    int* start  = count + M;        // M+1 entries
    int* cursor = start + M + 1;

    pack_kernel<<<128, 256, 0, stream>>>(W1, W1h, W1l, 128);
    pack_kernel<<<256, 256, 0, stream>>>(W2, W2h, W2l, 256);
    pack_kernel<<<384, 256, 0, stream>>>(P1, P1h, P1l, 384);
    pack_kernel<<<256, 256, 0, stream>>>(P2, P2h, P2l, 256);

    int gblocks = (M + MROWS - 1) / MROWS;
    int pxb = (M * 128 + 255) / 256;
    int eblocks = (E + 255) / 256;
    if (tierA || tierB) {
        prep_xb_kernel<<<pxb, 256, 0, stream>>>(x, t, xb, out, count, M);
        hist_node_kernel<<<eblocks, 256, 0, stream>>>(ei, count, E, M);
        scan_node_kernel<<<1, 1024, 0, stream>>>(count, start, cursor, M);
        reorder_csr_kernel<<<eblocks, 256, 0, stream>>>(ei, cursor, sorted, E, M);
        if (tierA) {
            gather_csr_kernel<true><<<(M + 7) / 8, 256, 0, stream>>>(xb, sorted, start, agg, M);
            mega_kernel<false><<<gblocks, 256, 0, stream>>>(
                x, t, xb, agg, W1h, W1l, b1, W2h, W2l, b2,
                P1h, P1l, pb1, P2h, P2l, pb2, P3, pb3, out, M);
        } else {
            gather_csr_kernel<false><<<(M + 7) / 8, 256, 0, stream>>>(xb, sorted, start, agg, M);
            mega_kernel<true><<<gblocks, 256, 0, stream>>>(
                x, t, xb, agg, W1h, W1l, b1, W2h, W2l, b2,
                P1h, P1l, pb1, P2h, P2l, pb2, P3, pb3, out, M);
        }
    } else {
        prep_kernel<<<pxb, 256, 0, stream>>>((unsigned short*)agg, out, M);
        scatter_kernel<<<(E + 7) / 8, 256, 0, stream>>>(ei, x, t, (unsigned short*)agg, E, M);
        mega_kernel<true><<<gblocks, 256, 0, stream>>>(
            x, t, nullptr, agg, W1h, W1l, b1, W2h, W2l, b2,
            P1h, P1l, pb1, P2h, P2l, pb2, P3, pb3, out, M);
    }
}

// Round 13
// 409.944 us; speedup vs baseline: 1.3742x; 1.1515x over previous
//
#include <hip/hip_runtime.h>
#include <hip/hip_bf16.h>

// ---------- bf16 helpers (raw ushort storage) ----------
__device__ __forceinline__ float b2f(unsigned short u) {
    union { float f; unsigned int i; } v; v.i = ((unsigned int)u) << 16; return v.f;
}
__device__ __forceinline__ unsigned short f2b(float f) {
    union { float f; unsigned int i; } v; v.f = f;
    unsigned int i = v.i;
    return (unsigned short)((i + 0x7FFFu + ((i >> 16) & 1u)) >> 16);   // RNE
}

typedef __bf16 bf16x8 __attribute__((ext_vector_type(8)));
typedef float  f32x4  __attribute__((ext_vector_type(4)));

#define MROWS 32

// 256-col LDS tile: row stride 256, XOR-16B swizzle
__device__ __forceinline__ int idx256(int r, int c) {
    return r * 256 + (((c >> 3) ^ (r & 31)) << 3) + (c & 7);
}
// 128-col LDS tile
__device__ __forceinline__ int idx128(int r, int c) {
    return r * 128 + ((((c >> 3) ^ r) & 15) << 3) + (c & 7);
}

// ---------- prep+hist: xb = bf16([x|t]); out[t_pred]=0; hist(count) ----------
// count must be zeroed (memsetAsync) before this kernel.
__global__ __launch_bounds__(256) void prep_xb_hist_kernel(
    const float* __restrict__ x, const float* __restrict__ t,
    const int* __restrict__ ei,
    unsigned short* __restrict__ xb, float* __restrict__ out,
    int* __restrict__ count, int E, int M)
{
    int idx = blockIdx.x * 256 + threadIdx.x;          // over M*128 >= E
    if (idx < M * 128) {
        int i = idx >> 7, j = idx & 127;
        xb[idx] = f2b((j < 127) ? x[(size_t)i * 127 + j] : t[i]);
    }
    if (idx < M) out[idx] = 0.0f;
    if (idx < E) {
        int s = ei[idx];
        int d = ei[E + idx];
        if ((unsigned)s < (unsigned)M && (unsigned)d < (unsigned)M)
            atomicAdd(&count[d], 1);
    }
}

// ---------- fallback prep: agg = 0; out[t_pred] = 0 ----------
__global__ __launch_bounds__(256) void prep_kernel(unsigned short* __restrict__ agg,
                                                   float* __restrict__ out, int M)
{
    int idx = blockIdx.x * 256 + threadIdx.x;
    if (idx < M * 128) agg[idx] = 0;
    if (idx < M) out[idx] = 0.0f;
}

// ---------- fallback scatter: bf16 packed global atomics ----------
__global__ __launch_bounds__(256) void scatter_kernel(
    const int* __restrict__ ei, const float* __restrict__ x,
    const float* __restrict__ t, unsigned short* __restrict__ agg, int E, int M)
{
    int e = blockIdx.x * 8 + (threadIdx.x >> 5);
    if (e >= E) return;
    int lane = threadIdx.x & 31;
    int s = ei[e];
    int d = ei[E + e];
    if ((unsigned)s >= (unsigned)M || (unsigned)d >= (unsigned)M) return;
    int f0 = lane * 4;
    const float* xr = x + (size_t)s * 127;
    float v0 = xr[f0];
    float v1 = xr[f0 + 1];
    float v2 = xr[f0 + 2];
    float v3 = (f0 + 3 < 127) ? xr[f0 + 3] : t[s];
    __hip_bfloat162* dp = (__hip_bfloat162*)(agg + (size_t)d * 128 + f0);
    __hip_bfloat162 a; a.x = __float2bfloat16(v0); a.y = __float2bfloat16(v1);
    __hip_bfloat162 b; b.x = __float2bfloat16(v2); b.y = __float2bfloat16(v3);
    unsafeAtomicAdd(dp,     a);
    unsafeAtomicAdd(dp + 1, b);
}

// ---------- S2: exclusive scan over M node counts (1 block, 1024 thr) --------
__global__ __launch_bounds__(1024) void scan_node_kernel(
    const int* __restrict__ count, int* __restrict__ start,
    int* __restrict__ cursor, int M)
{
    __shared__ int tsum[1024];
    int tid = threadIdx.x;
    int chunk = (M + 1023) >> 10;
    int lo = tid * chunk;
    int hi = lo + chunk; if (hi > M) hi = M;
    int s = 0;
    for (int i = lo; i < hi; ++i) s += count[i];
    tsum[tid] = s;
    __syncthreads();
    for (int off = 1; off < 1024; off <<= 1) {
        int a = (tid >= off) ? tsum[tid - off] : 0;
        __syncthreads();
        tsum[tid] += a;
        __syncthreads();
    }
    int run = tsum[tid] - s;
    for (int i = lo; i < hi; ++i) {
        start[i] = run;
        cursor[i] = run;
        run += count[i];
    }
    if (tid == 1023) start[M] = run;
}

// ---------- S3: reorder srcs into dst-sorted CSR order ----------
__global__ __launch_bounds__(256) void reorder_csr_kernel(
    const int* __restrict__ ei, int* __restrict__ cursor,
    int* __restrict__ sorted, int E, int M)
{
    int e = blockIdx.x * 256 + threadIdx.x;
    if (e >= E) return;
    int s = ei[e];
    int d = ei[E + e];
    if ((unsigned)s < (unsigned)M && (unsigned)d < (unsigned)M) {
        int slot = atomicAdd(&cursor[d], 1);
        sorted[slot] = s;
    }
}

// ---------- S4: CSR gather — quarter-wave (16 lanes) per node, uint4 rows ----
#define GU 8
template<bool F32AGG>
__global__ __launch_bounds__(256) void gather_csr_kernel(
    const unsigned short* __restrict__ xb, const int* __restrict__ sorted,
    const int* __restrict__ start, void* __restrict__ agg, int M)
{
    int node = blockIdx.x * 16 + (threadIdx.x >> 4);
    if (node >= M) return;
    int lane = threadIdx.x & 15;                // 16 lanes x uint4 = 256 B row
    int s0 = start[node], s1 = start[node + 1];
    float a[8];
    #pragma unroll
    for (int j = 0; j < 8; ++j) a[j] = 0.f;
    for (int base = s0; base < s1; base += GU) {
        int last = s1 - 1;
        uint4 rv[GU];
        #pragma unroll
        for (int g = 0; g < GU; ++g) {          // all row loads in flight first
            int i = base + g;
            int src = sorted[(i < s1) ? i : last];
            rv[g] = *(const uint4*)(xb + (size_t)src * 128 + lane * 8);
        }
        #pragma unroll
        for (int g = 0; g < GU; ++g) {
            if (base + g < s1) {
                a[0] += b2f((unsigned short)(rv[g].x & 0xffff));
                a[1] += b2f((unsigned short)(rv[g].x >> 16));
                a[2] += b2f((unsigned short)(rv[g].y & 0xffff));
                a[3] += b2f((unsigned short)(rv[g].y >> 16));
                a[4] += b2f((unsigned short)(rv[g].z & 0xffff));
                a[5] += b2f((unsigned short)(rv[g].z >> 16));
                a[6] += b2f((unsigned short)(rv[g].w & 0xffff));
                a[7] += b2f((unsigned short)(rv[g].w >> 16));
            }
        }
    }
    size_t o = (size_t)node * 128 + lane * 8;
    if (F32AGG) {
        float4 w0; w0.x = a[0]; w0.y = a[1]; w0.z = a[2]; w0.w = a[3];
        float4 w1; w1.x = a[4]; w1.y = a[5]; w1.z = a[6]; w1.w = a[7];
        *(float4*)((float*)agg + o)     = w0;
        *(float4*)((float*)agg + o + 4) = w1;
    } else {
        uint4 w;
        w.x = (unsigned)f2b(a[0]) | ((unsigned)f2b(a[1]) << 16);
        w.y = (unsigned)f2b(a[2]) | ((unsigned)f2b(a[3]) << 16);
        w.z = (unsigned)f2b(a[4]) | ((unsigned)f2b(a[5]) << 16);
        w.w = (unsigned)f2b(a[6]) | ((unsigned)f2b(a[7]) << 16);
        *(uint4*)((unsigned short*)agg + o) = w;
    }
}

// ---------- pack all weights in ONE launch -----------------------------------
// W1,W2 -> hi+lo planes; P1,P2 -> hi only (error budget analysis: predictor
// inputs are O(1), bf16 P-weights add ~0.003 absmax vs 0.036 threshold).
// layout per weight: packed idx = ((kt*16+nt)*64+lane)*8 + j,
// value = B[(kt*32+(lane>>4)*8+j)*256 + nt*16+(lane&15)]
__global__ __launch_bounds__(256) void pack_all_kernel(
    const float* __restrict__ W1, const float* __restrict__ W2,
    const float* __restrict__ P1, const float* __restrict__ P2,
    unsigned short* __restrict__ W1h, unsigned short* __restrict__ W1l,
    unsigned short* __restrict__ W2h, unsigned short* __restrict__ W2l,
    unsigned short* __restrict__ P1h, unsigned short* __restrict__ P2h)
{
    int idx = blockIdx.x * 256 + threadIdx.x;   // over (128+256+384+256)*256
    const float* B; unsigned short *Bh, *Bl; int loc;
    if (idx < 128 * 256)       { B = W1; Bh = W1h; Bl = W1l; loc = idx; }
    else if (idx < 384 * 256)  { B = W2; Bh = W2h; Bl = W2l; loc = idx - 128 * 256; }
    else if (idx < 768 * 256)  { B = P1; Bh = P1h; Bl = nullptr; loc = idx - 384 * 256; }
    else if (idx < 1024 * 256) { B = P2; Bh = P2h; Bl = nullptr; loc = idx - 768 * 256; }
    else return;
    int j    = loc & 7;
    int lane = (loc >> 3) & 63;
    int nt   = (loc >> 9) & 15;
    int kt   = loc >> 13;
    int k = kt * 32 + ((lane >> 4) * 8) + j;
    int n = nt * 16 + (lane & 15);
    float w = B[k * 256 + n];
    unsigned short hi = f2b(w);
    Bh[loc] = hi;
    if (Bl) Bl[loc] = f2b(w - b2f(hi));
}

// ---------- mega: 4 GEMMs + final dot, 32-row blocks, single 16 KB LDS -------
// W1/W2: split hi+lo (2 MFMAs); P1/P2: hi only (1 MFMA) -> 31% fewer MFMAs,
// 32% less weight traffic. NO __launch_bounds__ min-waves (R9/R11: spills).
template<bool BF16AGG>
__global__ __launch_bounds__(256) void mega_kernel(
    const float* __restrict__ x, const float* __restrict__ t,
    const unsigned short* __restrict__ xb,
    const void* __restrict__ aggv,
    const unsigned short* __restrict__ W1h, const unsigned short* __restrict__ W1l,
    const float* __restrict__ b1,
    const unsigned short* __restrict__ W2h, const unsigned short* __restrict__ W2l,
    const float* __restrict__ b2,
    const unsigned short* __restrict__ P1h, const float* __restrict__ pb1,
    const unsigned short* __restrict__ P2h, const float* __restrict__ pb2,
    const float* __restrict__ P3, const float* __restrict__ pb3,
    float* __restrict__ out, int M)
{
    __shared__ unsigned short U[MROWS * 256];   // 16 KB: h_in -> h1 -> h -> p1
    __shared__ float red[4 * MROWS];            // 512 B

    const int wave = threadIdx.x >> 6;
    const int lane = threadIdx.x & 63;
    const int lr   = lane & 15;
    const int quad = lane >> 4;
    const int lk   = quad * 8;
    const int rbase = quad * 4;
    const int row0 = blockIdx.x * MROWS;
    const int ntg0 = wave * 4;

    // ---- U[idx128] = bf16(x_in + agg): 32 rows x 128 cols ----
    {
        int r = threadIdx.x >> 3;            // 0..31
        int q = threadIdx.x & 7;             // 0..7, 16 cols each
        int gr = row0 + r; if (gr >= M) gr = M - 1;
        #pragma unroll
        for (int c8 = 0; c8 < 2; ++c8) {
            int c0 = q * 16 + c8 * 8;
            float av[8];
            if (BF16AGG) {
                const unsigned short* ar = (const unsigned short*)aggv + (size_t)gr * 128 + c0;
                uint4 u = *(const uint4*)ar;
                av[0]=b2f((unsigned short)(u.x&0xffff)); av[1]=b2f((unsigned short)(u.x>>16));
                av[2]=b2f((unsigned short)(u.y&0xffff)); av[3]=b2f((unsigned short)(u.y>>16));
                av[4]=b2f((unsigned short)(u.z&0xffff)); av[5]=b2f((unsigned short)(u.z>>16));
                av[6]=b2f((unsigned short)(u.w&0xffff)); av[7]=b2f((unsigned short)(u.w>>16));
            } else {
                const float* ar = (const float*)aggv + (size_t)gr * 128 + c0;
                float4 g0 = *(const float4*)ar, g1 = *(const float4*)(ar + 4);
                av[0]=g0.x; av[1]=g0.y; av[2]=g0.z; av[3]=g0.w;
                av[4]=g1.x; av[5]=g1.y; av[6]=g1.z; av[7]=g1.w;
            }
            union { unsigned short u[8]; uint4 v; } ob;
            if (xb) {
                union { uint4 v; unsigned short u[8]; } xv;
                xv.v = *(const uint4*)(xb + (size_t)gr * 128 + c0);
                #pragma unroll
                for (int j = 0; j < 8; ++j) ob.u[j] = f2b(b2f(xv.u[j]) + av[j]);
            } else {
                const float* xr = x + (size_t)gr * 127;
                #pragma unroll
                for (int j = 0; j < 8; ++j) {
                    int f = c0 + j;
                    float xval = (f < 127) ? xr[f] : t[gr];
                    ob.u[j] = f2b(xval + av[j]);
                }
            }
            *(uint4*)&U[idx128(r, c0)] = ob.v;
        }
    }
    __syncthreads();

    f32x4 acc[2][4];
    const f32x4 zero = {0.f, 0.f, 0.f, 0.f};

    // ======== stage 1: h1 = relu(h_in @ W1 + b1); U := h1 ========
    #pragma unroll
    for (int nt = 0; nt < 4; ++nt)
        #pragma unroll
        for (int rt = 0; rt < 2; ++rt) acc[rt][nt] = zero;

    for (int kt = 0; kt < 4; ++kt) {
        bf16x8 a[2];
        #pragma unroll
        for (int rt = 0; rt < 2; ++rt)
            a[rt] = *(const bf16x8*)&U[idx128(rt * 16 + lr, kt * 32 + lk)];
        #pragma unroll
        for (int nt = 0; nt < 4; ++nt) {
            size_t bofs = (size_t)((kt * 16 + ntg0 + nt) * 64 + lane) * 8;
            bf16x8 bh = *(const bf16x8*)(W1h + bofs);
            bf16x8 bl = *(const bf16x8*)(W1l + bofs);
            #pragma unroll
            for (int rt = 0; rt < 2; ++rt) {
                acc[rt][nt] = __builtin_amdgcn_mfma_f32_16x16x32_bf16(a[rt], bl, acc[rt][nt], 0, 0, 0);
                acc[rt][nt] = __builtin_amdgcn_mfma_f32_16x16x32_bf16(a[rt], bh, acc[rt][nt], 0, 0, 0);
            }
        }
    }
    __syncthreads();
    #pragma unroll
    for (int nt = 0; nt < 4; ++nt) {
        int col = (ntg0 + nt) * 16 + lr;
        float bv = b1[col];
        #pragma unroll
        for (int rt = 0; rt < 2; ++rt)
            #pragma unroll
            for (int r4 = 0; r4 < 4; ++r4)
                U[idx256(rt * 16 + rbase + r4, col)] = f2b(fmaxf(acc[rt][nt][r4] + bv, 0.f));
    }
    __syncthreads();

    // ======== stage 2: h = tanh(relu(h1 @ W2 + b2)); U := h ========
    #pragma unroll
    for (int nt = 0; nt < 4; ++nt)
        #pragma unroll
        for (int rt = 0; rt < 2; ++rt) acc[rt][nt] = zero;

    for (int kt = 0; kt < 8; ++kt) {
        bf16x8 a[2];
        #pragma unroll
        for (int rt = 0; rt < 2; ++rt)
            a[rt] = *(const bf16x8*)&U[idx256(rt * 16 + lr, kt * 32 + lk)];
        #pragma unroll
        for (int nt = 0; nt < 4; ++nt) {
            size_t bofs = (size_t)((kt * 16 + ntg0 + nt) * 64 + lane) * 8;
            bf16x8 bh = *(const bf16x8*)(W2h + bofs);
            bf16x8 bl = *(const bf16x8*)(W2l + bofs);
            #pragma unroll
            for (int rt = 0; rt < 2; ++rt) {
                acc[rt][nt] = __builtin_amdgcn_mfma_f32_16x16x32_bf16(a[rt], bl, acc[rt][nt], 0, 0, 0);
                acc[rt][nt] = __builtin_amdgcn_mfma_f32_16x16x32_bf16(a[rt], bh, acc[rt][nt], 0, 0, 0);
            }
        }
    }
    __syncthreads();
    #pragma unroll
    for (int nt = 0; nt < 4; ++nt) {
        int col = (ntg0 + nt) * 16 + lr;
        float bv = b2[col];
        #pragma unroll
        for (int rt = 0; rt < 2; ++rt)
            #pragma unroll
            for (int r4 = 0; r4 < 4; ++r4) {
                float v = fmaxf(acc[rt][nt][r4] + bv, 0.f);   // relu∘tanh == tanh∘relu
                float e = __expf(-2.f * v);
                U[idx256(rt * 16 + rbase + r4, col)] = f2b((1.f - e) / (1.f + e));
            }
    }
    __syncthreads();

    // ======== stage 3: p1 = lrelu([h | x_in] @ P1 + pb1); U := p1 ========
    #pragma unroll
    for (int nt = 0; nt < 4; ++nt)
        #pragma unroll
        for (int rt = 0; rt < 2; ++rt) acc[rt][nt] = zero;

    for (int kt = 0; kt < 12; ++kt) {
        bf16x8 a[2];
        if (kt < 8) {
            #pragma unroll
            for (int rt = 0; rt < 2; ++rt)
                a[rt] = *(const bf16x8*)&U[idx256(rt * 16 + lr, kt * 32 + lk)];
        } else if (xb) {
            #pragma unroll
            for (int rt = 0; rt < 2; ++rt) {
                int r = row0 + rt * 16 + lr; if (r >= M) r = M - 1;
                a[rt] = *(const bf16x8*)(xb + (size_t)r * 128 + (kt - 8) * 32 + lk);
            }
        } else {
            #pragma unroll
            for (int rt = 0; rt < 2; ++rt) {
                int r = row0 + rt * 16 + lr; if (r >= M) r = M - 1;
                int c0 = (kt - 8) * 32 + lk;
                const float* xr = x + (size_t)r * 127;
                union { unsigned short u[8]; bf16x8 v; } au;
                #pragma unroll
                for (int j = 0; j < 8; ++j) {
                    int f = c0 + j;
                    au.u[j] = f2b((f < 127) ? xr[f] : t[r]);
                }
                a[rt] = au.v;
            }
        }
        #pragma unroll
        for (int nt = 0; nt < 4; ++nt) {
            size_t bofs = (size_t)((kt * 16 + ntg0 + nt) * 64 + lane) * 8;
            bf16x8 bh = *(const bf16x8*)(P1h + bofs);
            #pragma unroll
            for (int rt = 0; rt < 2; ++rt)
                acc[rt][nt] = __builtin_amdgcn_mfma_f32_16x16x32_bf16(a[rt], bh, acc[rt][nt], 0, 0, 0);
        }
    }
    __syncthreads();
    #pragma unroll
    for (int nt = 0; nt < 4; ++nt) {
        int col = (ntg0 + nt) * 16 + lr;
        float bv = pb1[col];
        #pragma unroll
        for (int rt = 0; rt < 2; ++rt)
            #pragma unroll
            for (int r4 = 0; r4 < 4; ++r4) {
                float v = acc[rt][nt][r4] + bv;
                U[idx256(rt * 16 + rbase + r4, col)] = f2b((v > 0.f) ? v : 0.2f * v);
            }
    }
    __syncthreads();

    // ======== stage 4: p2 = lrelu(p1 @ P2 + pb2); pred = p2 . P3 + pb3 ========
    #pragma unroll
    for (int nt = 0; nt < 4; ++nt)
        #pragma unroll
        for (int rt = 0; rt < 2; ++rt) acc[rt][nt] = zero;

    for (int kt = 0; kt < 8; ++kt) {
        bf16x8 a[2];
        #pragma unroll
        for (int rt = 0; rt < 2; ++rt)
            a[rt] = *(const bf16x8*)&U[idx256(rt * 16 + lr, kt * 32 + lk)];
        #pragma unroll
        for (int nt = 0; nt < 4; ++nt) {
            size_t bofs = (size_t)((kt * 16 + ntg0 + nt) * 64 + lane) * 8;
            bf16x8 bh = *(const bf16x8*)(P2h + bofs);
            #pragma unroll
            for (int rt = 0; rt < 2; ++rt)
                acc[rt][nt] = __builtin_amdgcn_mfma_f32_16x16x32_bf16(a[rt], bh, acc[rt][nt], 0, 0, 0);
        }
    }
    float part[2][4];
    #pragma unroll
    for (int rt = 0; rt < 2; ++rt)
        #pragma unroll
        for (int r4 = 0; r4 < 4; ++r4) part[rt][r4] = 0.f;
    #pragma unroll
    for (int nt = 0; nt < 4; ++nt) {
        int col = (ntg0 + nt) * 16 + lr;
        float bv = pb2[col];
        float p3 = P3[col];
        #pragma unroll
        for (int rt = 0; rt < 2; ++rt)
            #pragma unroll
            for (int r4 = 0; r4 < 4; ++r4) {
                float v = acc[rt][nt][r4] + bv;
                v = (v > 0.f) ? v : 0.2f * v;
                part[rt][r4] += v * p3;
            }
    }
    #pragma unroll
    for (int rt = 0; rt < 2; ++rt)
        #pragma unroll
        for (int r4 = 0; r4 < 4; ++r4) {
            float s = part[rt][r4];
            s += __shfl_xor(s, 1);
            s += __shfl_xor(s, 2);
            s += __shfl_xor(s, 4);
            s += __shfl_xor(s, 8);
            if (lr == 0) red[wave * MROWS + rt * 16 + rbase + r4] = s;
        }
    __syncthreads();
    if (threadIdx.x < MROWS) {
        int row = row0 + threadIdx.x;
        if (row < M) {
            float s = red[threadIdx.x] + red[MROWS + threadIdx.x]
                    + red[2 * MROWS + threadIdx.x] + red[3 * MROWS + threadIdx.x] + pb3[0];
            out[M + row] = s;
        }
    }
}

extern "C" void kernel_launch(void* const* d_in, const int* in_sizes, int n_in,
                              void* d_out, int out_size, void* d_ws, size_t ws_size,
                              hipStream_t stream)
{
    const int M = in_sizes[1];                 // 50000
    const int E = in_sizes[3] / 2;             // 800000
    const float* x   = (const float*)d_in[0];
    const float* t   = (const float*)d_in[1];
    const int*   ei  = (const int*)d_in[3];
    const float* W1  = (const float*)d_in[4];
    const float* b1  = (const float*)d_in[5];
    const float* W2  = (const float*)d_in[6];
    const float* b2  = (const float*)d_in[7];
    const float* P1  = (const float*)d_in[8];
    const float* pb1 = (const float*)d_in[9];
    const float* P2  = (const float*)d_in[10];
    const float* pb2 = (const float*)d_in[11];
    const float* P3  = (const float*)d_in[12];
    const float* pb3 = (const float*)d_in[13];
    float* out = (float*)d_out;

    const size_t aggF32 = (size_t)M * 128 * 4;
    const size_t aggBF  = (size_t)M * 128 * 2;
    const size_t xbB    = (size_t)M * 128 * 2;
    // packed weights: W1 hi+lo, W2 hi+lo, P1 hi, P2 hi
    const size_t wB     = (size_t)(128 * 2 + 256 * 2 + 384 + 256) * 256 * 2;  // 720 KB
    const size_t sortB  = (size_t)E * 4;
    const size_t csrB   = (size_t)(3 * M + 2) * 4;
    char* ws = (char*)d_ws;
    auto al = [](size_t v) { return (v + 255) & ~(size_t)255; };

    bool tierA = ws_size >= al(aggF32) + al(xbB) + al(wB) + al(sortB) + al(csrB) + 4096;
    bool tierB = ws_size >= al(aggBF)  + al(xbB) + al(wB) + al(sortB) + al(csrB) + 4096;

    size_t aggBytes = tierA ? aggF32 : aggBF;
    void* agg = (void*)ws;
    unsigned short* xb = (unsigned short*)(ws + al(aggBytes));
    unsigned short* W1h = (unsigned short*)((char*)xb + al(xbB));
    unsigned short* W1l = W1h + 128 * 256;
    unsigned short* W2h = W1l + 128 * 256;
    unsigned short* W2l = W2h + 256 * 256;
    unsigned short* P1h = W2l + 256 * 256;
    unsigned short* P2h = P1h + 384 * 256;
    int* sorted = (int*)(P2h + 256 * 256);
    int* count  = sorted + E;
    int* start  = count + M;        // M+1 entries
    int* cursor = start + M + 1;

    int gblocks = (M + MROWS - 1) / MROWS;
    int pxb = (M * 128 + 255) / 256;
    int eblocks = (E + 255) / 256;

    pack_all_kernel<<<1024, 256, 0, stream>>>(W1, W2, P1, P2,
                                              W1h, W1l, W2h, W2l, P1h, P2h);

    if (tierA || tierB) {
        hipMemsetAsync(count, 0, (size_t)M * 4, stream);
        prep_xb_hist_kernel<<<pxb, 256, 0, stream>>>(x, t, ei, xb, out, count, E, M);
        scan_node_kernel<<<1, 1024, 0, stream>>>(count, start, cursor, M);
        reorder_csr_kernel<<<eblocks, 256, 0, stream>>>(ei, cursor, sorted, E, M);
        if (tierA) {
            gather_csr_kernel<true><<<(M + 15) / 16, 256, 0, stream>>>(xb, sorted, start, agg, M);
            mega_kernel<false><<<gblocks, 256, 0, stream>>>(
                x, t, xb, agg, W1h, W1l, b1, W2h, W2l, b2,
                P1h, pb1, P2h, pb2, P3, pb3, out, M);
        } else {
            gather_csr_kernel<false><<<(M + 15) / 16, 256, 0, stream>>>(xb, sorted, start, agg, M);
            mega_kernel<true><<<gblocks, 256, 0, stream>>>(
                x, t, xb, agg, W1h, W1l, b1, W2h, W2l, b2,
                P1h, pb1, P2h, pb2, P3, pb3, out, M);
        }
    } else {
        prep_kernel<<<pxb, 256, 0, stream>>>((unsigned short*)agg, out, M);
        scatter_kernel<<<(E + 7) / 8, 256, 0, stream>>>(ei, x, t, (unsigned short*)agg, E, M);
        mega_kernel<true><<<gblocks, 256, 0, stream>>>(
            x, t, nullptr, agg, W1h, W1l, b1, W2h, W2l, b2,
            P1h, pb1, P2h, pb2, P3, pb3, out, M);
    }
}

// Round 14
// 311.547 us; speedup vs baseline: 1.8083x; 1.3158x over previous
//
#include <hip/hip_runtime.h>
#include <hip/hip_bf16.h>

// ---------- bf16 helpers (raw ushort storage) ----------
__device__ __forceinline__ float b2f(unsigned short u) {
    union { float f; unsigned int i; } v; v.i = ((unsigned int)u) << 16; return v.f;
}
__device__ __forceinline__ unsigned short f2b(float f) {
    union { float f; unsigned int i; } v; v.f = f;
    unsigned int i = v.i;
    return (unsigned short)((i + 0x7FFFu + ((i >> 16) & 1u)) >> 16);   // RNE
}

typedef __bf16 bf16x8 __attribute__((ext_vector_type(8)));
typedef float  f32x4  __attribute__((ext_vector_type(4)));

#define MROWS 32

// 256-col LDS tile: row stride 256, XOR-16B swizzle
__device__ __forceinline__ int idx256(int r, int c) {
    return r * 256 + (((c >> 3) ^ (r & 31)) << 3) + (c & 7);
}
// 128-col LDS tile
__device__ __forceinline__ int idx128(int r, int c) {
    return r * 128 + ((((c >> 3) ^ r) & 15) << 3) + (c & 7);
}

// ---------- prep+hist: xb = bf16([x|t]); out[t_pred]=0; hist(count) ----------
// count must be zeroed (memsetAsync) before this kernel.
__global__ __launch_bounds__(256) void prep_xb_hist_kernel(
    const float* __restrict__ x, const float* __restrict__ t,
    const int* __restrict__ ei,
    unsigned short* __restrict__ xb, float* __restrict__ out,
    int* __restrict__ count, int E, int M)
{
    int idx = blockIdx.x * 256 + threadIdx.x;          // over M*128 >= E
    if (idx < M * 128) {
        int i = idx >> 7, j = idx & 127;
        xb[idx] = f2b((j < 127) ? x[(size_t)i * 127 + j] : t[i]);
    }
    if (idx < M) out[idx] = 0.0f;
    if (idx < E) {
        int s = ei[idx];
        int d = ei[E + idx];
        if ((unsigned)s < (unsigned)M && (unsigned)d < (unsigned)M)
            atomicAdd(&count[d], 1);
    }
}

// ---------- fallback prep: agg = 0; out[t_pred] = 0 ----------
__global__ __launch_bounds__(256) void prep_kernel(unsigned short* __restrict__ agg,
                                                   float* __restrict__ out, int M)
{
    int idx = blockIdx.x * 256 + threadIdx.x;
    if (idx < M * 128) agg[idx] = 0;
    if (idx < M) out[idx] = 0.0f;
}

// ---------- fallback scatter: bf16 packed global atomics ----------
__global__ __launch_bounds__(256) void scatter_kernel(
    const int* __restrict__ ei, const float* __restrict__ x,
    const float* __restrict__ t, unsigned short* __restrict__ agg, int E, int M)
{
    int e = blockIdx.x * 8 + (threadIdx.x >> 5);
    if (e >= E) return;
    int lane = threadIdx.x & 31;
    int s = ei[e];
    int d = ei[E + e];
    if ((unsigned)s >= (unsigned)M || (unsigned)d >= (unsigned)M) return;
    int f0 = lane * 4;
    const float* xr = x + (size_t)s * 127;
    float v0 = xr[f0];
    float v1 = xr[f0 + 1];
    float v2 = xr[f0 + 2];
    float v3 = (f0 + 3 < 127) ? xr[f0 + 3] : t[s];
    __hip_bfloat162* dp = (__hip_bfloat162*)(agg + (size_t)d * 128 + f0);
    __hip_bfloat162 a; a.x = __float2bfloat16(v0); a.y = __float2bfloat16(v1);
    __hip_bfloat162 b; b.x = __float2bfloat16(v2); b.y = __float2bfloat16(v3);
    unsafeAtomicAdd(dp,     a);
    unsafeAtomicAdd(dp + 1, b);
}

// ---------- hierarchical exclusive scan over M counts (3 tiny kernels) -------
// R13: single-block scan was 111 us (1 CU, strided serial loads). These three
// are all coalesced and multi-block.
__global__ __launch_bounds__(256) void scan_part1(
    const int* __restrict__ count, int* __restrict__ bsum, int M)
{
    __shared__ int sb[256];
    int i = blockIdx.x * 256 + threadIdx.x;
    sb[threadIdx.x] = (i < M) ? count[i] : 0;
    __syncthreads();
    #pragma unroll
    for (int off = 128; off > 0; off >>= 1) {
        if (threadIdx.x < off) sb[threadIdx.x] += sb[threadIdx.x + off];
        __syncthreads();
    }
    if (threadIdx.x == 0) bsum[blockIdx.x] = sb[0];
}

__global__ __launch_bounds__(1024) void scan_part2(int* __restrict__ bsum, int nb)
{
    __shared__ int sb[1024];
    int tid = threadIdx.x;
    int v = (tid < nb) ? bsum[tid] : 0;
    sb[tid] = v;
    __syncthreads();
    for (int off = 1; off < 1024; off <<= 1) {
        int a = (tid >= off) ? sb[tid - off] : 0;
        __syncthreads();
        sb[tid] += a;
        __syncthreads();
    }
    if (tid < nb) bsum[tid] = sb[tid] - v;     // exclusive
}

__global__ __launch_bounds__(256) void scan_part3(
    const int* __restrict__ count, const int* __restrict__ bsum,
    int* __restrict__ start, int* __restrict__ cursor, int M)
{
    __shared__ int sb[256];
    int tid = threadIdx.x;
    int i = blockIdx.x * 256 + tid;
    int v = (i < M) ? count[i] : 0;
    sb[tid] = v;
    __syncthreads();
    for (int off = 1; off < 256; off <<= 1) {
        int a = (tid >= off) ? sb[tid - off] : 0;
        __syncthreads();
        sb[tid] += a;
        __syncthreads();
    }
    int exc = sb[tid] - v + bsum[blockIdx.x];
    if (i < M) { start[i] = exc; cursor[i] = exc; }
    if (i == M - 1) start[M] = exc + v;
}

// ---------- S3: reorder srcs into dst-sorted CSR order ----------
__global__ __launch_bounds__(256) void reorder_csr_kernel(
    const int* __restrict__ ei, int* __restrict__ cursor,
    int* __restrict__ sorted, int E, int M)
{
    int e = blockIdx.x * 256 + threadIdx.x;
    if (e >= E) return;
    int s = ei[e];
    int d = ei[E + e];
    if ((unsigned)s < (unsigned)M && (unsigned)d < (unsigned)M) {
        int slot = atomicAdd(&cursor[d], 1);
        sorted[slot] = s;
    }
}

// ---------- S4: CSR gather — quarter-wave (16 lanes) per node, uint4 rows ----
#define GU 8
template<bool F32AGG>
__global__ __launch_bounds__(256) void gather_csr_kernel(
    const unsigned short* __restrict__ xb, const int* __restrict__ sorted,
    const int* __restrict__ start, void* __restrict__ agg, int M)
{
    int node = blockIdx.x * 16 + (threadIdx.x >> 4);
    if (node >= M) return;
    int lane = threadIdx.x & 15;                // 16 lanes x uint4 = 256 B row
    int s0 = start[node], s1 = start[node + 1];
    float a[8];
    #pragma unroll
    for (int j = 0; j < 8; ++j) a[j] = 0.f;
    for (int base = s0; base < s1; base += GU) {
        int last = s1 - 1;
        uint4 rv[GU];
        #pragma unroll
        for (int g = 0; g < GU; ++g) {          // all row loads in flight first
            int i = base + g;
            int src = sorted[(i < s1) ? i : last];
            rv[g] = *(const uint4*)(xb + (size_t)src * 128 + lane * 8);
        }
        #pragma unroll
        for (int g = 0; g < GU; ++g) {
            if (base + g < s1) {
                a[0] += b2f((unsigned short)(rv[g].x & 0xffff));
                a[1] += b2f((unsigned short)(rv[g].x >> 16));
                a[2] += b2f((unsigned short)(rv[g].y & 0xffff));
                a[3] += b2f((unsigned short)(rv[g].y >> 16));
                a[4] += b2f((unsigned short)(rv[g].z & 0xffff));
                a[5] += b2f((unsigned short)(rv[g].z >> 16));
                a[6] += b2f((unsigned short)(rv[g].w & 0xffff));
                a[7] += b2f((unsigned short)(rv[g].w >> 16));
            }
        }
    }
    size_t o = (size_t)node * 128 + lane * 8;
    if (F32AGG) {
        float4 w0; w0.x = a[0]; w0.y = a[1]; w0.z = a[2]; w0.w = a[3];
        float4 w1; w1.x = a[4]; w1.y = a[5]; w1.z = a[6]; w1.w = a[7];
        *(float4*)((float*)agg + o)     = w0;
        *(float4*)((float*)agg + o + 4) = w1;
    } else {
        uint4 w;
        w.x = (unsigned)f2b(a[0]) | ((unsigned)f2b(a[1]) << 16);
        w.y = (unsigned)f2b(a[2]) | ((unsigned)f2b(a[3]) << 16);
        w.z = (unsigned)f2b(a[4]) | ((unsigned)f2b(a[5]) << 16);
        w.w = (unsigned)f2b(a[6]) | ((unsigned)f2b(a[7]) << 16);
        *(uint4*)((unsigned short*)agg + o) = w;
    }
}

// ---------- pack all weights in ONE launch -----------------------------------
// W1,W2 -> hi+lo planes; P1,P2 -> hi only (error budget: bf16 P-weights add
// ~0.003 absmax vs 0.036 threshold; measured R13: 0.0117 total).
__global__ __launch_bounds__(256) void pack_all_kernel(
    const float* __restrict__ W1, const float* __restrict__ W2,
    const float* __restrict__ P1, const float* __restrict__ P2,
    unsigned short* __restrict__ W1h, unsigned short* __restrict__ W1l,
    unsigned short* __restrict__ W2h, unsigned short* __restrict__ W2l,
    unsigned short* __restrict__ P1h, unsigned short* __restrict__ P2h)
{
    int idx = blockIdx.x * 256 + threadIdx.x;   // over (128+256+384+256)*256
    const float* B; unsigned short *Bh, *Bl; int loc;
    if (idx < 128 * 256)       { B = W1; Bh = W1h; Bl = W1l; loc = idx; }
    else if (idx < 384 * 256)  { B = W2; Bh = W2h; Bl = W2l; loc = idx - 128 * 256; }
    else if (idx < 768 * 256)  { B = P1; Bh = P1h; Bl = nullptr; loc = idx - 384 * 256; }
    else if (idx < 1024 * 256) { B = P2; Bh = P2h; Bl = nullptr; loc = idx - 768 * 256; }
    else return;
    int j    = loc & 7;
    int lane = (loc >> 3) & 63;
    int nt   = (loc >> 9) & 15;
    int kt   = loc >> 13;
    int k = kt * 32 + ((lane >> 4) * 8) + j;
    int n = nt * 16 + (lane & 15);
    float w = B[k * 256 + n];
    unsigned short hi = f2b(w);
    Bh[loc] = hi;
    if (Bl) Bl[loc] = f2b(w - b2f(hi));
}

// ---------- mega: 4 GEMMs + final dot, 32-row blocks, single 16 KB LDS -------
// W1/W2: split hi+lo (2 MFMAs); P1/P2: hi only (1 MFMA).
// NO __launch_bounds__ min-waves (R9/R11: forced caps -> catastrophic spill).
template<bool BF16AGG>
__global__ __launch_bounds__(256) void mega_kernel(
    const float* __restrict__ x, const float* __restrict__ t,
    const unsigned short* __restrict__ xb,
    const void* __restrict__ aggv,
    const unsigned short* __restrict__ W1h, const unsigned short* __restrict__ W1l,
    const float* __restrict__ b1,
    const unsigned short* __restrict__ W2h, const unsigned short* __restrict__ W2l,
    const float* __restrict__ b2,
    const unsigned short* __restrict__ P1h, const float* __restrict__ pb1,
    const unsigned short* __restrict__ P2h, const float* __restrict__ pb2,
    const float* __restrict__ P3, const float* __restrict__ pb3,
    float* __restrict__ out, int M)
{
    __shared__ unsigned short U[MROWS * 256];   // 16 KB: h_in -> h1 -> h -> p1
    __shared__ float red[4 * MROWS];            // 512 B

    const int wave = threadIdx.x >> 6;
    const int lane = threadIdx.x & 63;
    const int lr   = lane & 15;
    const int quad = lane >> 4;
    const int lk   = quad * 8;
    const int rbase = quad * 4;
    const int row0 = blockIdx.x * MROWS;
    const int ntg0 = wave * 4;

    // ---- U[idx128] = bf16(x_in + agg): 32 rows x 128 cols ----
    {
        int r = threadIdx.x >> 3;            // 0..31
        int q = threadIdx.x & 7;             // 0..7, 16 cols each
        int gr = row0 + r; if (gr >= M) gr = M - 1;
        #pragma unroll
        for (int c8 = 0; c8 < 2; ++c8) {
            int c0 = q * 16 + c8 * 8;
            float av[8];
            if (BF16AGG) {
                const unsigned short* ar = (const unsigned short*)aggv + (size_t)gr * 128 + c0;
                uint4 u = *(const uint4*)ar;
                av[0]=b2f((unsigned short)(u.x&0xffff)); av[1]=b2f((unsigned short)(u.x>>16));
                av[2]=b2f((unsigned short)(u.y&0xffff)); av[3]=b2f((unsigned short)(u.y>>16));
                av[4]=b2f((unsigned short)(u.z&0xffff)); av[5]=b2f((unsigned short)(u.z>>16));
                av[6]=b2f((unsigned short)(u.w&0xffff)); av[7]=b2f((unsigned short)(u.w>>16));
            } else {
                const float* ar = (const float*)aggv + (size_t)gr * 128 + c0;
                float4 g0 = *(const float4*)ar, g1 = *(const float4*)(ar + 4);
                av[0]=g0.x; av[1]=g0.y; av[2]=g0.z; av[3]=g0.w;
                av[4]=g1.x; av[5]=g1.y; av[6]=g1.z; av[7]=g1.w;
            }
            union { unsigned short u[8]; uint4 v; } ob;
            if (xb) {
                union { uint4 v; unsigned short u[8]; } xv;
                xv.v = *(const uint4*)(xb + (size_t)gr * 128 + c0);
                #pragma unroll
                for (int j = 0; j < 8; ++j) ob.u[j] = f2b(b2f(xv.u[j]) + av[j]);
            } else {
                const float* xr = x + (size_t)gr * 127;
                #pragma unroll
                for (int j = 0; j < 8; ++j) {
                    int f = c0 + j;
                    float xval = (f < 127) ? xr[f] : t[gr];
                    ob.u[j] = f2b(xval + av[j]);
                }
            }
            *(uint4*)&U[idx128(r, c0)] = ob.v;
        }
    }
    __syncthreads();

    f32x4 acc[2][4];
    const f32x4 zero = {0.f, 0.f, 0.f, 0.f};

    // ======== stage 1: h1 = relu(h_in @ W1 + b1); U := h1 ========
    #pragma unroll
    for (int nt = 0; nt < 4; ++nt)
        #pragma unroll
        for (int rt = 0; rt < 2; ++rt) acc[rt][nt] = zero;

    for (int kt = 0; kt < 4; ++kt) {
        bf16x8 a[2];
        #pragma unroll
        for (int rt = 0; rt < 2; ++rt)
            a[rt] = *(const bf16x8*)&U[idx128(rt * 16 + lr, kt * 32 + lk)];
        #pragma unroll
        for (int nt = 0; nt < 4; ++nt) {
            size_t bofs = (size_t)((kt * 16 + ntg0 + nt) * 64 + lane) * 8;
            bf16x8 bh = *(const bf16x8*)(W1h + bofs);
            bf16x8 bl = *(const bf16x8*)(W1l + bofs);
            #pragma unroll
            for (int rt = 0; rt < 2; ++rt) {
                acc[rt][nt] = __builtin_amdgcn_mfma_f32_16x16x32_bf16(a[rt], bl, acc[rt][nt], 0, 0, 0);
                acc[rt][nt] = __builtin_amdgcn_mfma_f32_16x16x32_bf16(a[rt], bh, acc[rt][nt], 0, 0, 0);
            }
        }
    }
    __syncthreads();
    #pragma unroll
    for (int nt = 0; nt < 4; ++nt) {
        int col = (ntg0 + nt) * 16 + lr;
        float bv = b1[col];
        #pragma unroll
        for (int rt = 0; rt < 2; ++rt)
            #pragma unroll
            for (int r4 = 0; r4 < 4; ++r4)
                U[idx256(rt * 16 + rbase + r4, col)] = f2b(fmaxf(acc[rt][nt][r4] + bv, 0.f));
    }
    __syncthreads();

    // ======== stage 2: h = tanh(relu(h1 @ W2 + b2)); U := h ========
    #pragma unroll
    for (int nt = 0; nt < 4; ++nt)
        #pragma unroll
        for (int rt = 0; rt < 2; ++rt) acc[rt][nt] = zero;

    for (int kt = 0; kt < 8; ++kt) {
        bf16x8 a[2];
        #pragma unroll
        for (int rt = 0; rt < 2; ++rt)
            a[rt] = *(const bf16x8*)&U[idx256(rt * 16 + lr, kt * 32 + lk)];
        #pragma unroll
        for (int nt = 0; nt < 4; ++nt) {
            size_t bofs = (size_t)((kt * 16 + ntg0 + nt) * 64 + lane) * 8;
            bf16x8 bh = *(const bf16x8*)(W2h + bofs);
            bf16x8 bl = *(const bf16x8*)(W2l + bofs);
            #pragma unroll
            for (int rt = 0; rt < 2; ++rt) {
                acc[rt][nt] = __builtin_amdgcn_mfma_f32_16x16x32_bf16(a[rt], bl, acc[rt][nt], 0, 0, 0);
                acc[rt][nt] = __builtin_amdgcn_mfma_f32_16x16x32_bf16(a[rt], bh, acc[rt][nt], 0, 0, 0);
            }
        }
    }
    __syncthreads();
    #pragma unroll
    for (int nt = 0; nt < 4; ++nt) {
        int col = (ntg0 + nt) * 16 + lr;
        float bv = b2[col];
        #pragma unroll
        for (int rt = 0; rt < 2; ++rt)
            #pragma unroll
            for (int r4 = 0; r4 < 4; ++r4) {
                float v = fmaxf(acc[rt][nt][r4] + bv, 0.f);   // relu∘tanh == tanh∘relu
                float e = __expf(-2.f * v);
                U[idx256(rt * 16 + rbase + r4, col)] = f2b((1.f - e) / (1.f + e));
            }
    }
    __syncthreads();

    // ======== stage 3: p1 = lrelu([h | x_in] @ P1 + pb1); U := p1 ========
    #pragma unroll
    for (int nt = 0; nt < 4; ++nt)
        #pragma unroll
        for (int rt = 0; rt < 2; ++rt) acc[rt][nt] = zero;

    for (int kt = 0; kt < 12; ++kt) {
        bf16x8 a[2];
        if (kt < 8) {
            #pragma unroll
            for (int rt = 0; rt < 2; ++rt)
                a[rt] = *(const bf16x8*)&U[idx256(rt * 16 + lr, kt * 32 + lk)];
        } else if (xb) {
            #pragma unroll
            for (int rt = 0; rt < 2; ++rt) {
                int r = row0 + rt * 16 + lr; if (r >= M) r = M - 1;
                a[rt] = *(const bf16x8*)(xb + (size_t)r * 128 + (kt - 8) * 32 + lk);
            }
        } else {
            #pragma unroll
            for (int rt = 0; rt < 2; ++rt) {
                int r = row0 + rt * 16 + lr; if (r >= M) r = M - 1;
                int c0 = (kt - 8) * 32 + lk;
                const float* xr = x + (size_t)r * 127;
                union { unsigned short u[8]; bf16x8 v; } au;
                #pragma unroll
                for (int j = 0; j < 8; ++j) {
                    int f = c0 + j;
                    au.u[j] = f2b((f < 127) ? xr[f] : t[r]);
                }
                a[rt] = au.v;
            }
        }
        #pragma unroll
        for (int nt = 0; nt < 4; ++nt) {
            size_t bofs = (size_t)((kt * 16 + ntg0 + nt) * 64 + lane) * 8;
            bf16x8 bh = *(const bf16x8*)(P1h + bofs);
            #pragma unroll
            for (int rt = 0; rt < 2; ++rt)
                acc[rt][nt] = __builtin_amdgcn_mfma_f32_16x16x32_bf16(a[rt], bh, acc[rt][nt], 0, 0, 0);
        }
    }
    __syncthreads();
    #pragma unroll
    for (int nt = 0; nt < 4; ++nt) {
        int col = (ntg0 + nt) * 16 + lr;
        float bv = pb1[col];
        #pragma unroll
        for (int rt = 0; rt < 2; ++rt)
            #pragma unroll
            for (int r4 = 0; r4 < 4; ++r4) {
                float v = acc[rt][nt][r4] + bv;
                U[idx256(rt * 16 + rbase + r4, col)] = f2b((v > 0.f) ? v : 0.2f * v);
            }
    }
    __syncthreads();

    // ======== stage 4: p2 = lrelu(p1 @ P2 + pb2); pred = p2 . P3 + pb3 ========
    #pragma unroll
    for (int nt = 0; nt < 4; ++nt)
        #pragma unroll
        for (int rt = 0; rt < 2; ++rt) acc[rt][nt] = zero;

    for (int kt = 0; kt < 8; ++kt) {
        bf16x8 a[2];
        #pragma unroll
        for (int rt = 0; rt < 2; ++rt)
            a[rt] = *(const bf16x8*)&U[idx256(rt * 16 + lr, kt * 32 + lk)];
        #pragma unroll
        for (int nt = 0; nt < 4; ++nt) {
            size_t bofs = (size_t)((kt * 16 + ntg0 + nt) * 64 + lane) * 8;
            bf16x8 bh = *(const bf16x8*)(P2h + bofs);
            #pragma unroll
            for (int rt = 0; rt < 2; ++rt)
                acc[rt][nt] = __builtin_amdgcn_mfma_f32_16x16x32_bf16(a[rt], bh, acc[rt][nt], 0, 0, 0);
        }
    }
    float part[2][4];
    #pragma unroll
    for (int rt = 0; rt < 2; ++rt)
        #pragma unroll
        for (int r4 = 0; r4 < 4; ++r4) part[rt][r4] = 0.f;
    #pragma unroll
    for (int nt = 0; nt < 4; ++nt) {
        int col = (ntg0 + nt) * 16 + lr;
        float bv = pb2[col];
        float p3 = P3[col];
        #pragma unroll
        for (int rt = 0; rt < 2; ++rt)
            #pragma unroll
            for (int r4 = 0; r4 < 4; ++r4) {
                float v = acc[rt][nt][r4] + bv;
                v = (v > 0.f) ? v : 0.2f * v;
                part[rt][r4] += v * p3;
            }
    }
    #pragma unroll
    for (int rt = 0; rt < 2; ++rt)
        #pragma unroll
        for (int r4 = 0; r4 < 4; ++r4) {
            float s = part[rt][r4];
            s += __shfl_xor(s, 1);
            s += __shfl_xor(s, 2);
            s += __shfl_xor(s, 4);
            s += __shfl_xor(s, 8);
            if (lr == 0) red[wave * MROWS + rt * 16 + rbase + r4] = s;
        }
    __syncthreads();
    if (threadIdx.x < MROWS) {
        int row = row0 + threadIdx.x;
        if (row < M) {
            float s = red[threadIdx.x] + red[MROWS + threadIdx.x]
                    + red[2 * MROWS + threadIdx.x] + red[3 * MROWS + threadIdx.x] + pb3[0];
            out[M + row] = s;
        }
    }
}

extern "C" void kernel_launch(void* const* d_in, const int* in_sizes, int n_in,
                              void* d_out, int out_size, void* d_ws, size_t ws_size,
                              hipStream_t stream)
{
    const int M = in_sizes[1];                 // 50000
    const int E = in_sizes[3] / 2;             // 800000
    const float* x   = (const float*)d_in[0];
    const float* t   = (const float*)d_in[1];
    const int*   ei  = (const int*)d_in[3];
    const float* W1  = (const float*)d_in[4];
    const float* b1  = (const float*)d_in[5];
    const float* W2  = (const float*)d_in[6];
    const float* b2  = (const float*)d_in[7];
    const float* P1  = (const float*)d_in[8];
    const float* pb1 = (const float*)d_in[9];
    const float* P2  = (const float*)d_in[10];
    const float* pb2 = (const float*)d_in[11];
    const float* P3  = (const float*)d_in[12];
    const float* pb3 = (const float*)d_in[13];
    float* out = (float*)d_out;

    const size_t aggF32 = (size_t)M * 128 * 4;
    const size_t aggBF  = (size_t)M * 128 * 2;
    const size_t xbB    = (size_t)M * 128 * 2;
    const size_t wB     = (size_t)(128 * 2 + 256 * 2 + 384 + 256) * 256 * 2;  // 720 KB
    const size_t sortB  = (size_t)E * 4;
    const int    nb     = (M + 255) / 256;     // 196 scan blocks (<=1024 supported)
    const size_t csrB   = (size_t)(3 * M + 2 + nb) * 4;
    char* ws = (char*)d_ws;
    auto al = [](size_t v) { return (v + 255) & ~(size_t)255; };

    bool tierA = (ws_size >= al(aggF32) + al(xbB) + al(wB) + al(sortB) + al(csrB) + 4096) && nb <= 1024;
    bool tierB = (ws_size >= al(aggBF)  + al(xbB) + al(wB) + al(sortB) + al(csrB) + 4096) && nb <= 1024;

    size_t aggBytes = tierA ? aggF32 : aggBF;
    void* agg = (void*)ws;
    unsigned short* xb = (unsigned short*)(ws + al(aggBytes));
    unsigned short* W1h = (unsigned short*)((char*)xb + al(xbB));
    unsigned short* W1l = W1h + 128 * 256;
    unsigned short* W2h = W1l + 128 * 256;
    unsigned short* W2l = W2h + 256 * 256;
    unsigned short* P1h = W2l + 256 * 256;
    unsigned short* P2h = P1h + 384 * 256;
    int* sorted = (int*)(P2h + 256 * 256);
    int* count  = sorted + E;
    int* start  = count + M;        // M+1 entries
    int* cursor = start + M + 1;
    int* bsum   = cursor + M;

    int gblocks = (M + MROWS - 1) / MROWS;
    int pxb = (M * 128 + 255) / 256;
    int eblocks = (E + 255) / 256;

    pack_all_kernel<<<1024, 256, 0, stream>>>(W1, W2, P1, P2,
                                              W1h, W1l, W2h, W2l, P1h, P2h);

    if (tierA || tierB) {
        hipMemsetAsync(count, 0, (size_t)M * 4, stream);
        prep_xb_hist_kernel<<<pxb, 256, 0, stream>>>(x, t, ei, xb, out, count, E, M);
        scan_part1<<<nb, 256, 0, stream>>>(count, bsum, M);
        scan_part2<<<1, 1024, 0, stream>>>(bsum, nb);
        scan_part3<<<nb, 256, 0, stream>>>(count, bsum, start, cursor, M);
        reorder_csr_kernel<<<eblocks, 256, 0, stream>>>(ei, cursor, sorted, E, M);
        if (tierA) {
            gather_csr_kernel<true><<<(M + 15) / 16, 256, 0, stream>>>(xb, sorted, start, agg, M);
            mega_kernel<false><<<gblocks, 256, 0, stream>>>(
                x, t, xb, agg, W1h, W1l, b1, W2h, W2l, b2,
                P1h, pb1, P2h, pb2, P3, pb3, out, M);
        } else {
            gather_csr_kernel<false><<<(M + 15) / 16, 256, 0, stream>>>(xb, sorted, start, agg, M);
            mega_kernel<true><<<gblocks, 256, 0, stream>>>(
                x, t, xb, agg, W1h, W1l, b1, W2h, W2l, b2,
                P1h, pb1, P2h, pb2, P3, pb3, out, M);
        }
    } else {
        prep_kernel<<<pxb, 256, 0, stream>>>((unsigned short*)agg, out, M);
        scatter_kernel<<<(E + 7) / 8, 256, 0, stream>>>(ei, x, t, (unsigned short*)agg, E, M);
        mega_kernel<true><<<gblocks, 256, 0, stream>>>(
            x, t, nullptr, agg, W1h, W1l, b1, W2h, W2l, b2,
            P1h, pb1, P2h, pb2, P3, pb3, out, M);
    }
}